// Round 13
// baseline (240.635 us; speedup 1.0000x reference)
//
#include <hip/hip_runtime.h>
#include <hip/hip_bf16.h>
#include <stdint.h>

// ---------------------------------------------------------------------------
// CNNLSTM: conv stack (MFMA phases 2-4) -> LSTM(T=512,batch=1024,H=64) -> proj
// v13 (= v12 + LSTM step reorder):
//  prep_k: conv weights -> bf16 A-fragment layout in ws slot 0; BN fused.
//  conv:   A-fragments from global (L2-hot), no LDS weight staging.
//  LSTM:   256 blocks x 4 rows, 1 cell/lane; exp2-folded gates; 8-deep h
//          history; per-step order: hf reads -> duty pa reads -> z-MFMAs ->
//          AXN dribble (fills za stall) -> duty proj MFMA+stores (no vmcnt
//          drain before raw barrier) -> gate VALU -> c/h/cvt/ds_write ->
//          lgkmcnt(0) + s_barrier.  (v12 had AXN+proj after the h-write,
//          extending every wave's path to the barrier.)
// ws layout: slot 0 = W2a/T1a/T2a bf16 A-frags + F[512] f32; slots 1..512 = x_t.
// ---------------------------------------------------------------------------

typedef __attribute__((ext_vector_type(8))) short bf16x8;
typedef __attribute__((ext_vector_type(4))) float f32x4;

__device__ __forceinline__ uint16_t f2bf(float f) {
  union { float f; uint32_t i; } v; v.f = f;
  return (uint16_t)((v.i + 0x7FFFu + ((v.i >> 16) & 1u)) >> 16);  // RNE
}
__device__ __forceinline__ float frcp(float x) { return __builtin_amdgcn_rcpf(x); }
// pre-scaled variants: z already multiplied by log2e (sig) / 2*log2e (tanh)
__device__ __forceinline__ float fsig2(float z)  { return frcp(1.f + __builtin_amdgcn_exp2f(-z)); }
__device__ __forceinline__ float ftanh2(float z) { return 1.f - 2.f * frcp(1.f + __builtin_amdgcn_exp2f(z)); }

#define MFMA16(a, b, c) __builtin_amdgcn_mfma_f32_16x16x32_bf16(a, b, c, 0, 0, 0)

// ============================ prep kernel ===================================
__global__ __launch_bounds__(256) void prep_k(
    const float* __restrict__ w2p, const float* __restrict__ t1p,
    const float* __restrict__ t2p,
    const float* __restrict__ g1, const float* __restrict__ be1,
    const float* __restrict__ m1, const float* __restrict__ v1,
    const float* __restrict__ b1,
    const float* __restrict__ g2, const float* __restrict__ be2,
    const float* __restrict__ m2, const float* __restrict__ v2,
    const float* __restrict__ b2,
    const float* __restrict__ g3, const float* __restrict__ be3,
    const float* __restrict__ m3, const float* __restrict__ v3,
    const float* __restrict__ tb1, const float* __restrict__ tb2,
    uint16_t* __restrict__ W)
{
  int idx = blockIdx.x * 256 + threadIdx.x;
  if (idx < 8192) {
    int h = idx >> 7, k = idx & 127;
    W[idx] = f2bf(w2p[h * 128 + (k & 63) * 2 + (k >> 6)]);
  } else if (idx < 16384) {
    int i = idx - 8192; int h = i >> 7, k = i & 127;
    W[idx] = f2bf(t1p[(k & 63) * 128 + h * 2 + (k >> 6)]);
  } else if (idx < 24576) {
    int i = idx - 16384; int h = i >> 7, k = i & 127;
    W[idx] = f2bf(t2p[(k & 63) * 128 + h * 2 + (k >> 6)]);
  } else if (idx < 25088) {
    int i = idx - 24576;            // 0..511
    float* F = (float*)(W + 24576);
    int h = i & 63, sel = i >> 6;
    float val;
    if (sel == 0)      val = g1[h] * __builtin_amdgcn_rsqf(v1[h] + 1e-5f);
    else if (sel == 1) { float s = g1[h] * __builtin_amdgcn_rsqf(v1[h] + 1e-5f);
                         val = (b1[h] - m1[h]) * s + be1[h]; }
    else if (sel == 2) val = g2[h] * __builtin_amdgcn_rsqf(v2[h] + 1e-5f);
    else if (sel == 3) { float s = g2[h] * __builtin_amdgcn_rsqf(v2[h] + 1e-5f);
                         val = (b2[h] - m2[h]) * s + be2[h]; }
    else if (sel == 4) val = g3[h] * __builtin_amdgcn_rsqf(v3[h] + 1e-5f);
    else if (sel == 5) { float s = g3[h] * __builtin_amdgcn_rsqf(v3[h] + 1e-5f);
                         val = (tb1[h] - m3[h]) * s + be3[h]; }
    else if (sel == 6) val = 1.0f;
    else               val = tb2[h];
    F[i] = val;
  }
}

// ============================ conv stack ===================================
#define YT   72
#define NROW 84

template<int PHASE>
__device__ __forceinline__ void mfma_phase(
    const uint16_t* yin, uint16_t* yout, uint16_t* Xg,
    const uint16_t* __restrict__ wAg,          // global A-layout [64][128]
    const float* __restrict__ p_sc, const float* __restrict__ p_tc,
    int lane, int wv, int l0)
{
  const int m0 = wv * 16;
  const int lm = lane & 15, lq = lane >> 4;
  bf16x8 af[4];
#pragma unroll
  for (int kc = 0; kc < 4; ++kc)
    af[kc] = *(const bf16x8*)&wAg[(m0 + lm) * 128 + kc * 32 + lq * 8];
  float scr[4], tcr[4];
#pragma unroll
  for (int r = 0; r < 4; ++r) {
    int hr = m0 + lq * 4 + r;
    scr[r] = p_sc[hr]; tcr[r] = p_tc[hr];
  }
  const f32x4 Z = {0.f, 0.f, 0.f, 0.f};
#pragma unroll
  for (int nt = 0; nt < 5; ++nt) {
    f32x4 acc = Z;
#pragma unroll
    for (int kc = 0; kc < 4; ++kc) {
      int half = kc >> 1;
      int rT = nt * 16 + lm + 1 + (PHASE == 2 ? half : -half);
      bf16x8 bf_ = *(const bf16x8*)&yin[rT * YT + (kc & 1) * 32 + lq * 8];
      acc = MFMA16(af[kc], bf_, acc);
    }
    int il = nt * 16 + lm;
    int gl = l0 - 2 + il;
#pragma unroll
    for (int r = 0; r < 4; ++r) {
      int h = m0 + lq * 4 + r;
      float v = fmaxf(acc[r] * scr[r] + tcr[r], 0.f);
      if constexpr (PHASE == 2) {
        if (il < 66) yout[(il + 1) * YT + h] = (gl >= 0 && gl < 1022) ? f2bf(v) : (uint16_t)0;
      } else if constexpr (PHASE == 3) {
        if (il >= 1 && il < 66) yout[(il + 1) * YT + h] = (gl >= 0 && gl < 1023) ? f2bf(v) : (uint16_t)0;
      } else {
        if (il >= 2 && il < 66) Xg[(size_t)gl * 64 + h] = f2bf(v);
      }
    }
  }
}

__global__ __launch_bounds__(256, 6) void conv_stack_k(
    const float* __restrict__ inp, const float* __restrict__ w1p,
    const float* __restrict__ F,
    const uint16_t* __restrict__ W2a, const uint16_t* __restrict__ T1a,
    const uint16_t* __restrict__ T2a,
    uint16_t* __restrict__ X)
{
  __shared__ __align__(16) uint16_t yTA[NROW * YT];
  __shared__ __align__(16) uint16_t yTB[NROW * YT];
  __shared__ float xs[6][YT];
  const int tid  = threadIdx.x;
  const int lane = tid & 63;
  const int wv   = tid >> 6;
  const int t    = blockIdx.y;
  const int l0   = blockIdx.x * 64;

  for (int i = tid; i < 6 * YT; i += 256) {
    int c = i % 6, il = i / 6;
    int gl = l0 - 2 + il;
    float v = 0.f;
    if (gl >= 0 && gl < 1024) v = inp[(size_t)t * 6144 + (size_t)gl * 6 + c];
    xs[c][il] = v;
  }

  // ---- phase 1 (VALU): y1 = relu(bn1(conv1(x))), write yTA rows 1..67
  {
    const int h = lane;
    float wr[12];
#pragma unroll
    for (int i = 0; i < 6; ++i) {
      float2 q = *(const float2*)(w1p + h * 12 + i * 2);
      wr[i * 2] = q.x; wr[i * 2 + 1] = q.y;
    }
    float sc = F[h], tc = F[64 + h];
    __syncthreads();   // xs ready
#pragma unroll 1
    for (int base = wv * 4; base < 67; base += 16) {
      float a0 = 0, a1 = 0, a2 = 0, a3 = 0;
#pragma unroll
      for (int c = 0; c < 6; ++c) {
        float4 v = *(const float4*)&xs[c][base];
        float s4 = xs[c][base + 4];
        float k0 = wr[c * 2], k1 = wr[c * 2 + 1];
        a0 += v.x * k0 + v.y * k1;
        a1 += v.y * k0 + v.z * k1;
        a2 += v.z * k0 + v.w * k1;
        a3 += v.w * k0 + s4 * k1;
      }
      float r[4] = {a0, a1, a2, a3};
#pragma unroll
      for (int j = 0; j < 4; ++j) {
        int il = base + j;
        if (il < 67) {
          int gl = l0 - 2 + il;
          yTA[(il + 1) * YT + h] =
              (gl >= 0 && gl < 1023) ? f2bf(fmaxf(r[j] * sc + tc, 0.f)) : (uint16_t)0;
        }
      }
    }
  }
  __syncthreads();

  mfma_phase<2>(yTA, yTB, nullptr, W2a, F + 128, F + 192, lane, wv, l0);
  __syncthreads();
  mfma_phase<3>(yTB, yTA, nullptr, T1a, F + 256, F + 320, lane, wv, l0);
  __syncthreads();
  mfma_phase<4>(yTA, nullptr, X + (size_t)(t + 1) * 65536, T2a,
                F + 384, F + 448, lane, wv, l0);
}

// ============================== LSTM v13 ====================================
// 256 blocks x 4 batch rows, 4 waves x 16 gate-cols, 1 cell/lane.
#define HSTR 72

// one step; K_ literal 0..7 (hh slot & step-in-batch), DG literal dribble gate
#define LSTM_STEP(T_, K_, AXC, DG, XD, AXN) do {                               \
    /* 1: on-chain LDS reads (and duty pa reads, latency-overlapped) */        \
    bf16x8 hf0_ = *(const bf16x8*)&hh[((K_) + 7) & 7][(lm >> 2) * HSTR + lq * 8];      \
    bf16x8 hf1_ = *(const bf16x8*)&hh[((K_) + 7) & 7][(lm >> 2) * HSTR + 32 + lq * 8]; \
    bool duty_ = (((K_) & 3) == 0) && (T_) > 0 && wv == (((T_) >> 2) & 3);     \
    bf16x8 pa0_, pa1_;                                                         \
    if (duty_) {                                                               \
      pa0_ = *(const bf16x8*)&hh[((K_) ^ 4) + (lm & 3)][(lm >> 2) * HSTR + lq * 8];      \
      pa1_ = *(const bf16x8*)&hh[((K_) ^ 4) + (lm & 3)][(lm >> 2) * HSTR + 32 + lq * 8]; \
    }                                                                          \
    /* 2: on-chain z-MFMAs */                                                  \
    f32x4 za0_ = MFMA16(hf0_, bfr[0][2], AXC[0]);                              \
    f32x4 zb0_ = MFMA16(hf1_, bfr[0][3], Z4);                                  \
    f32x4 za1_ = MFMA16(hf0_, bfr[1][2], AXC[1]);                              \
    f32x4 zb1_ = MFMA16(hf1_, bfr[1][3], Z4);                                  \
    f32x4 za2_ = MFMA16(hf0_, bfr[2][2], AXC[2]);                              \
    f32x4 zb2_ = MFMA16(hf1_, bfr[2][3], Z4);                                  \
    f32x4 za3_ = MFMA16(hf0_, bfr[3][2], AXC[3]);                              \
    f32x4 zb3_ = MFMA16(hf1_, bfr[3][3], Z4);                                  \
    /* 3: off-chain work fills the za stall window */                          \
    AXN[DG] = MFMA16(XD[1], bfr[DG][1], MFMA16(XD[0], bfr[DG][0], seeds[DG])); \
    if (duty_) {                                                               \
      f32x4 pr_ = MFMA16(pa1_, owf1, MFMA16(pa0_, owf0, Z4));                  \
      if (lm == 0) {                                                           \
        outp[(size_t)((T_) - 4) * 1024 + l0 + lq] = pr_[0] + obv;              \
        outp[(size_t)((T_) - 3) * 1024 + l0 + lq] = pr_[1] + obv;              \
        outp[(size_t)((T_) - 2) * 1024 + l0 + lq] = pr_[2] + obv;              \
        outp[(size_t)((T_) - 1) * 1024 + l0 + lq] = pr_[3] + obv;              \
      }                                                                        \
    }                                                                          \
    /* 4: on-chain pointwise */                                                \
    float ii_ = fsig2(za0_[(K_) & 3] + zb0_[(K_) & 3]);                        \
    float ff_ = fsig2(za1_[(K_) & 3] + zb1_[(K_) & 3]);                        \
    float gg_ = ftanh2(za2_[(K_) & 3] + zb2_[(K_) & 3]);                       \
    float oo_ = fsig2(za3_[(K_) & 3] + zb3_[(K_) & 3]);                        \
    creg  = ff_ * creg + ii_ * gg_;                                            \
    float th_ = 1.f - 2.f * frcp(1.f + __builtin_amdgcn_exp2f(creg * 2.88539008177793f)); \
    hprev = oo_ * th_;                                                         \
    uint32_t hw_;                                                              \
    asm("v_cvt_pk_bf16_f32 %0, %1, %2" : "=v"(hw_) : "v"(hprev), "v"(0.f));    \
    hh[(K_)][lq * HSTR + hcol] = (uint16_t)hw_;                                \
    asm volatile("s_waitcnt lgkmcnt(0)" ::: "memory");                         \
    __builtin_amdgcn_s_barrier();                                              \
    asm volatile("" ::: "memory");                                             \
  } while (0)

__global__ __launch_bounds__(256) void lstm_k(
    const float* __restrict__ h0p, const float* __restrict__ c0p,
    const float* __restrict__ wihp, const float* __restrict__ whhp,
    const float* __restrict__ bihp, const float* __restrict__ bhhp,
    const float* __restrict__ owp, const float* __restrict__ obp,
    uint16_t* __restrict__ Xb, float* __restrict__ outp)
{
  __shared__ __align__(16) uint16_t hh[8][4 * HSTR];   // 8-deep h history
  const int tid  = threadIdx.x;
  const int lane = tid & 63;
  const int wv   = tid >> 6;
  const int lm   = lane & 15;
  const int lq   = lane >> 4;
  const int l0   = blockIdx.x << 2;        // 4 batch rows per block
  const int hcol = (wv << 4) | lm;
  const f32x4 Z4 = {0.f, 0.f, 0.f, 0.f};
  const float L2E = 1.44269504088896340736f;

  // B weights, pre-scaled: i,f,o x log2e ; g x 2*log2e
  bf16x8 bfr[4][4];
#pragma unroll
  for (int nt = 0; nt < 4; ++nt) {
    float sg = (nt == 2) ? 2.f * L2E : L2E;
    int n = nt * 64 + hcol;
#pragma unroll
    for (int kc = 0; kc < 4; ++kc) {
      int k0 = kc * 32 + lq * 8;
      const float* src = (k0 < 64) ? (wihp + (size_t)n * 64 + k0)
                                   : (whhp + (size_t)n * 64 + (k0 - 64));
      bf16x8 f;
#pragma unroll
      for (int j = 0; j < 8; ++j) f[j] = (short)f2bf(src[j] * sg);
      bfr[nt][kc] = f;
    }
  }
  float bi0 = (bihp[hcol]       + bhhp[hcol])       * L2E;
  float bi1 = (bihp[64 + hcol]  + bhhp[64 + hcol])  * L2E;
  float bi2 = (bihp[128 + hcol] + bhhp[128 + hcol]) * 2.f * L2E;
  float bi3 = (bihp[192 + hcol] + bhhp[192 + hcol]) * L2E;
  f32x4 seeds[4];
  seeds[0] = f32x4{bi0, bi0, bi0, bi0};
  seeds[1] = f32x4{bi1, bi1, bi1, bi1};
  seeds[2] = f32x4{bi2, bi2, bi2, bi2};
  seeds[3] = f32x4{bi3, bi3, bi3, bi3};
  float obv = obp[0];

  // projection B-fragment: col 0 holds ow (true units)
  bf16x8 owf0 = {0, 0, 0, 0, 0, 0, 0, 0}, owf1 = {0, 0, 0, 0, 0, 0, 0, 0};
  if (lm == 0) {
#pragma unroll
    for (int j = 0; j < 8; ++j) {
      owf0[j] = (short)f2bf(owp[lq * 8 + j]);
      owf1[j] = (short)f2bf(owp[32 + lq * 8 + j]);
    }
  }

  // one cell per lane: (batch row lq, h-col hcol)
  float creg  = c0p[(size_t)(l0 + lq) * 64 + hcol];
  float hprev = 0.f;

  // stage h0 -> hh[7] ("step -1")
  {
    int row = tid >> 6, col = tid & 63;
    hh[7][row * HSTR + col] = f2bf(h0p[(size_t)(l0 + row) * 64 + col]);
  }

  // running x pointers: batch t0 reads slots t0+1..t0+4
  const uint16_t* pA = Xb + (size_t)(1 + (lm & 3)) * 65536
                     + (size_t)(l0 + (lm >> 2)) * 64 + lq * 8;
  const uint16_t* pB = pA + (size_t)4 * 65536;
  bf16x8 xA[2], xB[2];
  xA[0] = *(const bf16x8*)pA; xA[1] = *(const bf16x8*)(pA + 32);
  pA += (size_t)8 * 65536;
  xB[0] = *(const bf16x8*)pB; xB[1] = *(const bf16x8*)(pB + 32);
  pB += (size_t)8 * 65536;

  f32x4 axA[4], axB[4];
#pragma unroll
  for (int g = 0; g < 4; ++g)
    axA[g] = MFMA16(xA[1], bfr[g][1], MFMA16(xA[0], bfr[g][0], seeds[g]));
  __syncthreads();

#pragma unroll 1
  for (int t0 = 0; t0 < 512; t0 += 8) {
    if (t0 + 8 < 512) {          // xA <- batch t0+8 (dribbled at steps 4-7)
      xA[0] = *(const bf16x8*)pA; xA[1] = *(const bf16x8*)(pA + 32);
      pA += (size_t)8 * 65536;
    }
    LSTM_STEP(t0 + 0, 0, axA, 0, xB, axB);
    LSTM_STEP(t0 + 1, 1, axA, 1, xB, axB);
    LSTM_STEP(t0 + 2, 2, axA, 2, xB, axB);
    LSTM_STEP(t0 + 3, 3, axA, 3, xB, axB);
    if (t0 + 12 < 512) {         // xB <- batch t0+12 (dribbled next iter 0-3)
      xB[0] = *(const bf16x8*)pB; xB[1] = *(const bf16x8*)(pB + 32);
      pB += (size_t)8 * 65536;
    }
    LSTM_STEP(t0 + 4, 4, axB, 0, xA, axA);
    LSTM_STEP(t0 + 5, 5, axB, 1, xA, axA);
    LSTM_STEP(t0 + 6, 6, axB, 2, xA, axA);
    LSTM_STEP(t0 + 7, 7, axB, 3, xA, axA);
  }

  // post-loop duty: project steps 508-511 from hh slots 4-7 (wave 0)
  if (wv == 0) {
    bf16x8 pa0 = *(const bf16x8*)&hh[4 + (lm & 3)][(lm >> 2) * HSTR + lq * 8];
    bf16x8 pa1 = *(const bf16x8*)&hh[4 + (lm & 3)][(lm >> 2) * HSTR + 32 + lq * 8];
    f32x4 pr = MFMA16(pa1, owf1, MFMA16(pa0, owf0, Z4));
    if (lm == 0) {
      outp[(size_t)508 * 1024 + l0 + lq] = pr[0] + obv;
      outp[(size_t)509 * 1024 + l0 + lq] = pr[1] + obv;
      outp[(size_t)510 * 1024 + l0 + lq] = pr[2] + obv;
      outp[(size_t)511 * 1024 + l0 + lq] = pr[3] + obv;
    }
  }

  // hT at out+524288, cT at out+589824 (fp32)
  outp[524288 + (size_t)(l0 + lq) * 64 + hcol] = hprev;
  outp[589824 + (size_t)(l0 + lq) * 64 + hcol] = creg;
}

// ============================== launch =====================================
extern "C" void kernel_launch(void* const* d_in, const int* in_sizes, int n_in,
                              void* d_out, int out_size, void* d_ws, size_t ws_size,
                              hipStream_t stream)
{
  (void)in_sizes; (void)n_in; (void)out_size;
  if (ws_size < (size_t)513 * 65536 * 2) return;   // ws guard

  const float* inp = (const float*)d_in[0];
  const float* h0p = (const float*)d_in[1];
  const float* c0p = (const float*)d_in[2];
  const float* w1  = (const float*)d_in[3];
  const float* b1  = (const float*)d_in[4];
  const float* g1  = (const float*)d_in[5];
  const float* be1 = (const float*)d_in[6];
  const float* m1  = (const float*)d_in[7];
  const float* v1  = (const float*)d_in[8];
  const float* w2  = (const float*)d_in[9];
  const float* b2  = (const float*)d_in[10];
  const float* g2  = (const float*)d_in[11];
  const float* be2 = (const float*)d_in[12];
  const float* m2  = (const float*)d_in[13];
  const float* v2  = (const float*)d_in[14];
  const float* tw1 = (const float*)d_in[15];
  const float* tb1 = (const float*)d_in[16];
  const float* g3  = (const float*)d_in[17];
  const float* be3 = (const float*)d_in[18];
  const float* m3  = (const float*)d_in[19];
  const float* v3  = (const float*)d_in[20];
  const float* tw2 = (const float*)d_in[21];
  const float* tb2 = (const float*)d_in[22];
  const float* wih = (const float*)d_in[23];
  const float* whh = (const float*)d_in[24];
  const float* bih = (const float*)d_in[25];
  const float* bhh = (const float*)d_in[26];
  const float* ow  = (const float*)d_in[27];
  const float* ob  = (const float*)d_in[28];

  uint16_t* Xb   = (uint16_t*)d_ws;
  float*    outp = (float*)d_out;

  // slot 0 of Xb: W2a[0,8192) T1a[8192,16384) T2a[16384,24576) F(f32 x512)
  const uint16_t* W2a = Xb;
  const uint16_t* T1a = Xb + 8192;
  const uint16_t* T2a = Xb + 16384;
  const float*    F   = (const float*)(Xb + 24576);

  prep_k<<<98, 256, 0, stream>>>(w2, tw1, tw2,
                                 g1, be1, m1, v1, b1,
                                 g2, be2, m2, v2, b2,
                                 g3, be3, m3, v3, tb1, tb2, Xb);
  conv_stack_k<<<dim3(16, 512), 256, 0, stream>>>(inp, w1, F, W2a, T1a, T2a, Xb);
  lstm_k<<<256, 256, 0, stream>>>(h0p, c0p, wih, whh, bih, bhh, ow, ob, Xb, outp);
}

// Round 14
// 220.530 us; speedup vs baseline: 1.0912x; 1.0912x over previous
//
#include <hip/hip_runtime.h>
#include <hip/hip_bf16.h>
#include <stdint.h>

// ---------------------------------------------------------------------------
// CNNLSTM: conv stack (MFMA phases 2-4) -> LSTM(T=512,batch=1024,H=64) -> proj
// v14 (= v12 exactly, + chained z-MFMAs):
//  prep_k: conv weights -> bf16 A-fragment layout in ws slot 0; BN fused.
//  conv:   A-fragments from global (L2-hot), no LDS weight staging.
//  LSTM:   256 blocks x 4 rows, 1 cell/lane; exp2-folded gates; 8-deep h
//          history; batched duty-wave projection; AXN dribble placed AFTER
//          the h ds_write (its 2 MFMA issues cover the ds_write latency so
//          lgkmcnt(0) retires immediately -- v13 proved moving it regresses).
//  change: z-gate MFMAs chained (4 dependent pairs) instead of split
//          8 + 4 VALU adds -- same pipe timing, 4 fewer adds on each gate
//          chain, 4 fewer live accumulators (v10-proven pattern).
// ws layout: slot 0 = W2a/T1a/T2a bf16 A-frags + F[512] f32; slots 1..512 = x_t.
// ---------------------------------------------------------------------------

typedef __attribute__((ext_vector_type(8))) short bf16x8;
typedef __attribute__((ext_vector_type(4))) float f32x4;

__device__ __forceinline__ uint16_t f2bf(float f) {
  union { float f; uint32_t i; } v; v.f = f;
  return (uint16_t)((v.i + 0x7FFFu + ((v.i >> 16) & 1u)) >> 16);  // RNE
}
__device__ __forceinline__ float frcp(float x) { return __builtin_amdgcn_rcpf(x); }
// pre-scaled variants: z already multiplied by log2e (sig) / 2*log2e (tanh)
__device__ __forceinline__ float fsig2(float z)  { return frcp(1.f + __builtin_amdgcn_exp2f(-z)); }
__device__ __forceinline__ float ftanh2(float z) { return 1.f - 2.f * frcp(1.f + __builtin_amdgcn_exp2f(z)); }

#define MFMA16(a, b, c) __builtin_amdgcn_mfma_f32_16x16x32_bf16(a, b, c, 0, 0, 0)

// ============================ prep kernel ===================================
__global__ __launch_bounds__(256) void prep_k(
    const float* __restrict__ w2p, const float* __restrict__ t1p,
    const float* __restrict__ t2p,
    const float* __restrict__ g1, const float* __restrict__ be1,
    const float* __restrict__ m1, const float* __restrict__ v1,
    const float* __restrict__ b1,
    const float* __restrict__ g2, const float* __restrict__ be2,
    const float* __restrict__ m2, const float* __restrict__ v2,
    const float* __restrict__ b2,
    const float* __restrict__ g3, const float* __restrict__ be3,
    const float* __restrict__ m3, const float* __restrict__ v3,
    const float* __restrict__ tb1, const float* __restrict__ tb2,
    uint16_t* __restrict__ W)
{
  int idx = blockIdx.x * 256 + threadIdx.x;
  if (idx < 8192) {
    int h = idx >> 7, k = idx & 127;
    W[idx] = f2bf(w2p[h * 128 + (k & 63) * 2 + (k >> 6)]);
  } else if (idx < 16384) {
    int i = idx - 8192; int h = i >> 7, k = i & 127;
    W[idx] = f2bf(t1p[(k & 63) * 128 + h * 2 + (k >> 6)]);
  } else if (idx < 24576) {
    int i = idx - 16384; int h = i >> 7, k = i & 127;
    W[idx] = f2bf(t2p[(k & 63) * 128 + h * 2 + (k >> 6)]);
  } else if (idx < 25088) {
    int i = idx - 24576;            // 0..511
    float* F = (float*)(W + 24576);
    int h = i & 63, sel = i >> 6;
    float val;
    if (sel == 0)      val = g1[h] * __builtin_amdgcn_rsqf(v1[h] + 1e-5f);
    else if (sel == 1) { float s = g1[h] * __builtin_amdgcn_rsqf(v1[h] + 1e-5f);
                         val = (b1[h] - m1[h]) * s + be1[h]; }
    else if (sel == 2) val = g2[h] * __builtin_amdgcn_rsqf(v2[h] + 1e-5f);
    else if (sel == 3) { float s = g2[h] * __builtin_amdgcn_rsqf(v2[h] + 1e-5f);
                         val = (b2[h] - m2[h]) * s + be2[h]; }
    else if (sel == 4) val = g3[h] * __builtin_amdgcn_rsqf(v3[h] + 1e-5f);
    else if (sel == 5) { float s = g3[h] * __builtin_amdgcn_rsqf(v3[h] + 1e-5f);
                         val = (tb1[h] - m3[h]) * s + be3[h]; }
    else if (sel == 6) val = 1.0f;
    else               val = tb2[h];
    F[i] = val;
  }
}

// ============================ conv stack ===================================
#define YT   72
#define NROW 84

template<int PHASE>
__device__ __forceinline__ void mfma_phase(
    const uint16_t* yin, uint16_t* yout, uint16_t* Xg,
    const uint16_t* __restrict__ wAg,          // global A-layout [64][128]
    const float* __restrict__ p_sc, const float* __restrict__ p_tc,
    int lane, int wv, int l0)
{
  const int m0 = wv * 16;
  const int lm = lane & 15, lq = lane >> 4;
  bf16x8 af[4];
#pragma unroll
  for (int kc = 0; kc < 4; ++kc)
    af[kc] = *(const bf16x8*)&wAg[(m0 + lm) * 128 + kc * 32 + lq * 8];
  float scr[4], tcr[4];
#pragma unroll
  for (int r = 0; r < 4; ++r) {
    int hr = m0 + lq * 4 + r;
    scr[r] = p_sc[hr]; tcr[r] = p_tc[hr];
  }
  const f32x4 Z = {0.f, 0.f, 0.f, 0.f};
#pragma unroll
  for (int nt = 0; nt < 5; ++nt) {
    f32x4 acc = Z;
#pragma unroll
    for (int kc = 0; kc < 4; ++kc) {
      int half = kc >> 1;
      int rT = nt * 16 + lm + 1 + (PHASE == 2 ? half : -half);
      bf16x8 bf_ = *(const bf16x8*)&yin[rT * YT + (kc & 1) * 32 + lq * 8];
      acc = MFMA16(af[kc], bf_, acc);
    }
    int il = nt * 16 + lm;
    int gl = l0 - 2 + il;
#pragma unroll
    for (int r = 0; r < 4; ++r) {
      int h = m0 + lq * 4 + r;
      float v = fmaxf(acc[r] * scr[r] + tcr[r], 0.f);
      if constexpr (PHASE == 2) {
        if (il < 66) yout[(il + 1) * YT + h] = (gl >= 0 && gl < 1022) ? f2bf(v) : (uint16_t)0;
      } else if constexpr (PHASE == 3) {
        if (il >= 1 && il < 66) yout[(il + 1) * YT + h] = (gl >= 0 && gl < 1023) ? f2bf(v) : (uint16_t)0;
      } else {
        if (il >= 2 && il < 66) Xg[(size_t)gl * 64 + h] = f2bf(v);
      }
    }
  }
}

__global__ __launch_bounds__(256, 6) void conv_stack_k(
    const float* __restrict__ inp, const float* __restrict__ w1p,
    const float* __restrict__ F,
    const uint16_t* __restrict__ W2a, const uint16_t* __restrict__ T1a,
    const uint16_t* __restrict__ T2a,
    uint16_t* __restrict__ X)
{
  __shared__ __align__(16) uint16_t yTA[NROW * YT];
  __shared__ __align__(16) uint16_t yTB[NROW * YT];
  __shared__ float xs[6][YT];
  const int tid  = threadIdx.x;
  const int lane = tid & 63;
  const int wv   = tid >> 6;
  const int t    = blockIdx.y;
  const int l0   = blockIdx.x * 64;

  for (int i = tid; i < 6 * YT; i += 256) {
    int c = i % 6, il = i / 6;
    int gl = l0 - 2 + il;
    float v = 0.f;
    if (gl >= 0 && gl < 1024) v = inp[(size_t)t * 6144 + (size_t)gl * 6 + c];
    xs[c][il] = v;
  }

  // ---- phase 1 (VALU): y1 = relu(bn1(conv1(x))), write yTA rows 1..67
  {
    const int h = lane;
    float wr[12];
#pragma unroll
    for (int i = 0; i < 6; ++i) {
      float2 q = *(const float2*)(w1p + h * 12 + i * 2);
      wr[i * 2] = q.x; wr[i * 2 + 1] = q.y;
    }
    float sc = F[h], tc = F[64 + h];
    __syncthreads();   // xs ready
#pragma unroll 1
    for (int base = wv * 4; base < 67; base += 16) {
      float a0 = 0, a1 = 0, a2 = 0, a3 = 0;
#pragma unroll
      for (int c = 0; c < 6; ++c) {
        float4 v = *(const float4*)&xs[c][base];
        float s4 = xs[c][base + 4];
        float k0 = wr[c * 2], k1 = wr[c * 2 + 1];
        a0 += v.x * k0 + v.y * k1;
        a1 += v.y * k0 + v.z * k1;
        a2 += v.z * k0 + v.w * k1;
        a3 += v.w * k0 + s4 * k1;
      }
      float r[4] = {a0, a1, a2, a3};
#pragma unroll
      for (int j = 0; j < 4; ++j) {
        int il = base + j;
        if (il < 67) {
          int gl = l0 - 2 + il;
          yTA[(il + 1) * YT + h] =
              (gl >= 0 && gl < 1023) ? f2bf(fmaxf(r[j] * sc + tc, 0.f)) : (uint16_t)0;
        }
      }
    }
  }
  __syncthreads();

  mfma_phase<2>(yTA, yTB, nullptr, W2a, F + 128, F + 192, lane, wv, l0);
  __syncthreads();
  mfma_phase<3>(yTB, yTA, nullptr, T1a, F + 256, F + 320, lane, wv, l0);
  __syncthreads();
  mfma_phase<4>(yTA, nullptr, X + (size_t)(t + 1) * 65536, T2a,
                F + 384, F + 448, lane, wv, l0);
}

// ============================== LSTM v14 ====================================
// 256 blocks x 4 batch rows, 4 waves x 16 gate-cols, 1 cell/lane.
// Step order = v12 (proven): duty proj -> chained z-MFMAs -> pointwise ->
// h-write -> AXN dribble (covers ds_write latency) -> lgkmcnt(0)+barrier.
#define HSTR 72

// one step; K_ literal 0..7 (hh slot & step-in-batch), DG literal dribble gate
#define LSTM_STEP(T_, K_, AXC, DG, XD, AXN) do {                               \
    bf16x8 hf0_ = *(const bf16x8*)&hh[((K_) + 7) & 7][(lm >> 2) * HSTR + lq * 8];      \
    bf16x8 hf1_ = *(const bf16x8*)&hh[((K_) + 7) & 7][(lm >> 2) * HSTR + 32 + lq * 8]; \
    if ((((K_) & 3) == 0) && (T_) > 0 && wv == (((T_) >> 2) & 3)) {            \
      bf16x8 pa0_ = *(const bf16x8*)&hh[((K_) ^ 4) + (lm & 3)][(lm >> 2) * HSTR + lq * 8];      \
      bf16x8 pa1_ = *(const bf16x8*)&hh[((K_) ^ 4) + (lm & 3)][(lm >> 2) * HSTR + 32 + lq * 8]; \
      f32x4 pr_ = MFMA16(pa1_, owf1, MFMA16(pa0_, owf0, Z4));                  \
      if (lm == 0) {                                                           \
        outp[(size_t)((T_) - 4) * 1024 + l0 + lq] = pr_[0] + obv;              \
        outp[(size_t)((T_) - 3) * 1024 + l0 + lq] = pr_[1] + obv;              \
        outp[(size_t)((T_) - 2) * 1024 + l0 + lq] = pr_[2] + obv;              \
        outp[(size_t)((T_) - 1) * 1024 + l0 + lq] = pr_[3] + obv;              \
      }                                                                        \
    }                                                                          \
    f32x4 z0_ = MFMA16(hf1_, bfr[0][3], MFMA16(hf0_, bfr[0][2], AXC[0]));      \
    f32x4 z1_ = MFMA16(hf1_, bfr[1][3], MFMA16(hf0_, bfr[1][2], AXC[1]));      \
    f32x4 z2_ = MFMA16(hf1_, bfr[2][3], MFMA16(hf0_, bfr[2][2], AXC[2]));      \
    f32x4 z3_ = MFMA16(hf1_, bfr[3][3], MFMA16(hf0_, bfr[3][2], AXC[3]));      \
    float ii_ = fsig2(z0_[(K_) & 3]);                                          \
    float ff_ = fsig2(z1_[(K_) & 3]);                                          \
    float gg_ = ftanh2(z2_[(K_) & 3]);                                         \
    float oo_ = fsig2(z3_[(K_) & 3]);                                          \
    creg  = ff_ * creg + ii_ * gg_;                                            \
    float th_ = 1.f - 2.f * frcp(1.f + __builtin_amdgcn_exp2f(creg * 2.88539008177793f)); \
    hprev = oo_ * th_;                                                         \
    uint32_t hw_;                                                              \
    asm("v_cvt_pk_bf16_f32 %0, %1, %2" : "=v"(hw_) : "v"(hprev), "v"(0.f));    \
    hh[(K_)][lq * HSTR + hcol] = (uint16_t)hw_;                                \
    AXN[DG] = MFMA16(XD[1], bfr[DG][1], MFMA16(XD[0], bfr[DG][0], seeds[DG])); \
    asm volatile("s_waitcnt lgkmcnt(0)" ::: "memory");                         \
    __builtin_amdgcn_s_barrier();                                              \
    asm volatile("" ::: "memory");                                             \
  } while (0)

__global__ __launch_bounds__(256) void lstm_k(
    const float* __restrict__ h0p, const float* __restrict__ c0p,
    const float* __restrict__ wihp, const float* __restrict__ whhp,
    const float* __restrict__ bihp, const float* __restrict__ bhhp,
    const float* __restrict__ owp, const float* __restrict__ obp,
    uint16_t* __restrict__ Xb, float* __restrict__ outp)
{
  __shared__ __align__(16) uint16_t hh[8][4 * HSTR];   // 8-deep h history
  const int tid  = threadIdx.x;
  const int lane = tid & 63;
  const int wv   = tid >> 6;
  const int lm   = lane & 15;
  const int lq   = lane >> 4;
  const int l0   = blockIdx.x << 2;        // 4 batch rows per block
  const int hcol = (wv << 4) | lm;
  const f32x4 Z4 = {0.f, 0.f, 0.f, 0.f};
  const float L2E = 1.44269504088896340736f;

  // B weights, pre-scaled: i,f,o x log2e ; g x 2*log2e
  bf16x8 bfr[4][4];
#pragma unroll
  for (int nt = 0; nt < 4; ++nt) {
    float sg = (nt == 2) ? 2.f * L2E : L2E;
    int n = nt * 64 + hcol;
#pragma unroll
    for (int kc = 0; kc < 4; ++kc) {
      int k0 = kc * 32 + lq * 8;
      const float* src = (k0 < 64) ? (wihp + (size_t)n * 64 + k0)
                                   : (whhp + (size_t)n * 64 + (k0 - 64));
      bf16x8 f;
#pragma unroll
      for (int j = 0; j < 8; ++j) f[j] = (short)f2bf(src[j] * sg);
      bfr[nt][kc] = f;
    }
  }
  float bi0 = (bihp[hcol]       + bhhp[hcol])       * L2E;
  float bi1 = (bihp[64 + hcol]  + bhhp[64 + hcol])  * L2E;
  float bi2 = (bihp[128 + hcol] + bhhp[128 + hcol]) * 2.f * L2E;
  float bi3 = (bihp[192 + hcol] + bhhp[192 + hcol]) * L2E;
  f32x4 seeds[4];
  seeds[0] = f32x4{bi0, bi0, bi0, bi0};
  seeds[1] = f32x4{bi1, bi1, bi1, bi1};
  seeds[2] = f32x4{bi2, bi2, bi2, bi2};
  seeds[3] = f32x4{bi3, bi3, bi3, bi3};
  float obv = obp[0];

  // projection B-fragment: col 0 holds ow (true units)
  bf16x8 owf0 = {0, 0, 0, 0, 0, 0, 0, 0}, owf1 = {0, 0, 0, 0, 0, 0, 0, 0};
  if (lm == 0) {
#pragma unroll
    for (int j = 0; j < 8; ++j) {
      owf0[j] = (short)f2bf(owp[lq * 8 + j]);
      owf1[j] = (short)f2bf(owp[32 + lq * 8 + j]);
    }
  }

  // one cell per lane: (batch row lq, h-col hcol)
  float creg  = c0p[(size_t)(l0 + lq) * 64 + hcol];
  float hprev = 0.f;

  // stage h0 -> hh[7] ("step -1")
  {
    int row = tid >> 6, col = tid & 63;
    hh[7][row * HSTR + col] = f2bf(h0p[(size_t)(l0 + row) * 64 + col]);
  }

  // running x pointers: batch t0 reads slots t0+1..t0+4
  const uint16_t* pA = Xb + (size_t)(1 + (lm & 3)) * 65536
                     + (size_t)(l0 + (lm >> 2)) * 64 + lq * 8;
  const uint16_t* pB = pA + (size_t)4 * 65536;
  bf16x8 xA[2], xB[2];
  xA[0] = *(const bf16x8*)pA; xA[1] = *(const bf16x8*)(pA + 32);
  pA += (size_t)8 * 65536;
  xB[0] = *(const bf16x8*)pB; xB[1] = *(const bf16x8*)(pB + 32);
  pB += (size_t)8 * 65536;

  f32x4 axA[4], axB[4];
#pragma unroll
  for (int g = 0; g < 4; ++g)
    axA[g] = MFMA16(xA[1], bfr[g][1], MFMA16(xA[0], bfr[g][0], seeds[g]));
  __syncthreads();

#pragma unroll 1
  for (int t0 = 0; t0 < 512; t0 += 8) {
    if (t0 + 8 < 512) {          // xA <- batch t0+8 (dribbled at steps 4-7)
      xA[0] = *(const bf16x8*)pA; xA[1] = *(const bf16x8*)(pA + 32);
      pA += (size_t)8 * 65536;
    }
    LSTM_STEP(t0 + 0, 0, axA, 0, xB, axB);
    LSTM_STEP(t0 + 1, 1, axA, 1, xB, axB);
    LSTM_STEP(t0 + 2, 2, axA, 2, xB, axB);
    LSTM_STEP(t0 + 3, 3, axA, 3, xB, axB);
    if (t0 + 12 < 512) {         // xB <- batch t0+12 (dribbled next iter 0-3)
      xB[0] = *(const bf16x8*)pB; xB[1] = *(const bf16x8*)(pB + 32);
      pB += (size_t)8 * 65536;
    }
    LSTM_STEP(t0 + 4, 4, axB, 0, xA, axA);
    LSTM_STEP(t0 + 5, 5, axB, 1, xA, axA);
    LSTM_STEP(t0 + 6, 6, axB, 2, xA, axA);
    LSTM_STEP(t0 + 7, 7, axB, 3, xA, axA);
  }

  // post-loop duty: project steps 508-511 from hh slots 4-7 (wave 0)
  if (wv == 0) {
    bf16x8 pa0 = *(const bf16x8*)&hh[4 + (lm & 3)][(lm >> 2) * HSTR + lq * 8];
    bf16x8 pa1 = *(const bf16x8*)&hh[4 + (lm & 3)][(lm >> 2) * HSTR + 32 + lq * 8];
    f32x4 pr = MFMA16(pa1, owf1, MFMA16(pa0, owf0, Z4));
    if (lm == 0) {
      outp[(size_t)508 * 1024 + l0 + lq] = pr[0] + obv;
      outp[(size_t)509 * 1024 + l0 + lq] = pr[1] + obv;
      outp[(size_t)510 * 1024 + l0 + lq] = pr[2] + obv;
      outp[(size_t)511 * 1024 + l0 + lq] = pr[3] + obv;
    }
  }

  // hT at out+524288, cT at out+589824 (fp32)
  outp[524288 + (size_t)(l0 + lq) * 64 + hcol] = hprev;
  outp[589824 + (size_t)(l0 + lq) * 64 + hcol] = creg;
}

// ============================== launch =====================================
extern "C" void kernel_launch(void* const* d_in, const int* in_sizes, int n_in,
                              void* d_out, int out_size, void* d_ws, size_t ws_size,
                              hipStream_t stream)
{
  (void)in_sizes; (void)n_in; (void)out_size;
  if (ws_size < (size_t)513 * 65536 * 2) return;   // ws guard

  const float* inp = (const float*)d_in[0];
  const float* h0p = (const float*)d_in[1];
  const float* c0p = (const float*)d_in[2];
  const float* w1  = (const float*)d_in[3];
  const float* b1  = (const float*)d_in[4];
  const float* g1  = (const float*)d_in[5];
  const float* be1 = (const float*)d_in[6];
  const float* m1  = (const float*)d_in[7];
  const float* v1  = (const float*)d_in[8];
  const float* w2  = (const float*)d_in[9];
  const float* b2  = (const float*)d_in[10];
  const float* g2  = (const float*)d_in[11];
  const float* be2 = (const float*)d_in[12];
  const float* m2  = (const float*)d_in[13];
  const float* v2  = (const float*)d_in[14];
  const float* tw1 = (const float*)d_in[15];
  const float* tb1 = (const float*)d_in[16];
  const float* g3  = (const float*)d_in[17];
  const float* be3 = (const float*)d_in[18];
  const float* m3  = (const float*)d_in[19];
  const float* v3  = (const float*)d_in[20];
  const float* tw2 = (const float*)d_in[21];
  const float* tb2 = (const float*)d_in[22];
  const float* wih = (const float*)d_in[23];
  const float* whh = (const float*)d_in[24];
  const float* bih = (const float*)d_in[25];
  const float* bhh = (const float*)d_in[26];
  const float* ow  = (const float*)d_in[27];
  const float* ob  = (const float*)d_in[28];

  uint16_t* Xb   = (uint16_t*)d_ws;
  float*    outp = (float*)d_out;

  // slot 0 of Xb: W2a[0,8192) T1a[8192,16384) T2a[16384,24576) F(f32 x512)
  const uint16_t* W2a = Xb;
  const uint16_t* T1a = Xb + 8192;
  const uint16_t* T2a = Xb + 16384;
  const float*    F   = (const float*)(Xb + 24576);

  prep_k<<<98, 256, 0, stream>>>(w2, tw1, tw2,
                                 g1, be1, m1, v1, b1,
                                 g2, be2, m2, v2, b2,
                                 g3, be3, m3, v3, tb1, tb2, Xb);
  conv_stack_k<<<dim3(16, 512), 256, 0, stream>>>(inp, w1, F, W2a, T1a, T2a, Xb);
  lstm_k<<<256, 256, 0, stream>>>(h0p, c0p, wih, whh, bih, bhh, ow, ob, Xb, outp);
}

// Round 15
// 209.171 us; speedup vs baseline: 1.1504x; 1.0543x over previous
//
#include <hip/hip_runtime.h>
#include <hip/hip_bf16.h>
#include <stdint.h>

// ---------------------------------------------------------------------------
// CNNLSTM: conv stack (MFMA phases 2-4) -> LSTM(T=512,batch=1024,H=64) -> proj
// v15 (= v14 + dedicated projection wave):
//  prep_k: conv weights -> bf16 A-fragment layout in ws slot 0; BN fused.
//  conv:   A-fragments from global (L2-hot), no LDS weight staging.
//  LSTM:   256 blocks x 320 threads: waves 0-3 = compute (4 rows, 1 cell/lane,
//          exp2-folded gates, 8-deep h history, AXN dribble after h-write),
//          wave 4 = projection (reads 4-slot hh window twice per 8-step batch,
//          col-0 ow MFMA, 4 stores) -- removes the v14 duty-wave straggler
//          (+~120cyc barrier skew every 4th step) from the compute path.
//          Barrier protocol: both paths execute exactly 8 s_barriers/batch.
// ws layout: slot 0 = W2a/T1a/T2a bf16 A-frags + F[512] f32; slots 1..512 = x_t.
// ---------------------------------------------------------------------------

typedef __attribute__((ext_vector_type(8))) short bf16x8;
typedef __attribute__((ext_vector_type(4))) float f32x4;

__device__ __forceinline__ uint16_t f2bf(float f) {
  union { float f; uint32_t i; } v; v.f = f;
  return (uint16_t)((v.i + 0x7FFFu + ((v.i >> 16) & 1u)) >> 16);  // RNE
}
__device__ __forceinline__ float frcp(float x) { return __builtin_amdgcn_rcpf(x); }
// pre-scaled variants: z already multiplied by log2e (sig) / 2*log2e (tanh)
__device__ __forceinline__ float fsig2(float z)  { return frcp(1.f + __builtin_amdgcn_exp2f(-z)); }
__device__ __forceinline__ float ftanh2(float z) { return 1.f - 2.f * frcp(1.f + __builtin_amdgcn_exp2f(z)); }

#define MFMA16(a, b, c) __builtin_amdgcn_mfma_f32_16x16x32_bf16(a, b, c, 0, 0, 0)

// ============================ prep kernel ===================================
__global__ __launch_bounds__(256) void prep_k(
    const float* __restrict__ w2p, const float* __restrict__ t1p,
    const float* __restrict__ t2p,
    const float* __restrict__ g1, const float* __restrict__ be1,
    const float* __restrict__ m1, const float* __restrict__ v1,
    const float* __restrict__ b1,
    const float* __restrict__ g2, const float* __restrict__ be2,
    const float* __restrict__ m2, const float* __restrict__ v2,
    const float* __restrict__ b2,
    const float* __restrict__ g3, const float* __restrict__ be3,
    const float* __restrict__ m3, const float* __restrict__ v3,
    const float* __restrict__ tb1, const float* __restrict__ tb2,
    uint16_t* __restrict__ W)
{
  int idx = blockIdx.x * 256 + threadIdx.x;
  if (idx < 8192) {
    int h = idx >> 7, k = idx & 127;
    W[idx] = f2bf(w2p[h * 128 + (k & 63) * 2 + (k >> 6)]);
  } else if (idx < 16384) {
    int i = idx - 8192; int h = i >> 7, k = i & 127;
    W[idx] = f2bf(t1p[(k & 63) * 128 + h * 2 + (k >> 6)]);
  } else if (idx < 24576) {
    int i = idx - 16384; int h = i >> 7, k = i & 127;
    W[idx] = f2bf(t2p[(k & 63) * 128 + h * 2 + (k >> 6)]);
  } else if (idx < 25088) {
    int i = idx - 24576;            // 0..511
    float* F = (float*)(W + 24576);
    int h = i & 63, sel = i >> 6;
    float val;
    if (sel == 0)      val = g1[h] * __builtin_amdgcn_rsqf(v1[h] + 1e-5f);
    else if (sel == 1) { float s = g1[h] * __builtin_amdgcn_rsqf(v1[h] + 1e-5f);
                         val = (b1[h] - m1[h]) * s + be1[h]; }
    else if (sel == 2) val = g2[h] * __builtin_amdgcn_rsqf(v2[h] + 1e-5f);
    else if (sel == 3) { float s = g2[h] * __builtin_amdgcn_rsqf(v2[h] + 1e-5f);
                         val = (b2[h] - m2[h]) * s + be2[h]; }
    else if (sel == 4) val = g3[h] * __builtin_amdgcn_rsqf(v3[h] + 1e-5f);
    else if (sel == 5) { float s = g3[h] * __builtin_amdgcn_rsqf(v3[h] + 1e-5f);
                         val = (tb1[h] - m3[h]) * s + be3[h]; }
    else if (sel == 6) val = 1.0f;
    else               val = tb2[h];
    F[i] = val;
  }
}

// ============================ conv stack ===================================
#define YT   72
#define NROW 84

template<int PHASE>
__device__ __forceinline__ void mfma_phase(
    const uint16_t* yin, uint16_t* yout, uint16_t* Xg,
    const uint16_t* __restrict__ wAg,          // global A-layout [64][128]
    const float* __restrict__ p_sc, const float* __restrict__ p_tc,
    int lane, int wv, int l0)
{
  const int m0 = wv * 16;
  const int lm = lane & 15, lq = lane >> 4;
  bf16x8 af[4];
#pragma unroll
  for (int kc = 0; kc < 4; ++kc)
    af[kc] = *(const bf16x8*)&wAg[(m0 + lm) * 128 + kc * 32 + lq * 8];
  float scr[4], tcr[4];
#pragma unroll
  for (int r = 0; r < 4; ++r) {
    int hr = m0 + lq * 4 + r;
    scr[r] = p_sc[hr]; tcr[r] = p_tc[hr];
  }
  const f32x4 Z = {0.f, 0.f, 0.f, 0.f};
#pragma unroll
  for (int nt = 0; nt < 5; ++nt) {
    f32x4 acc = Z;
#pragma unroll
    for (int kc = 0; kc < 4; ++kc) {
      int half = kc >> 1;
      int rT = nt * 16 + lm + 1 + (PHASE == 2 ? half : -half);
      bf16x8 bf_ = *(const bf16x8*)&yin[rT * YT + (kc & 1) * 32 + lq * 8];
      acc = MFMA16(af[kc], bf_, acc);
    }
    int il = nt * 16 + lm;
    int gl = l0 - 2 + il;
#pragma unroll
    for (int r = 0; r < 4; ++r) {
      int h = m0 + lq * 4 + r;
      float v = fmaxf(acc[r] * scr[r] + tcr[r], 0.f);
      if constexpr (PHASE == 2) {
        if (il < 66) yout[(il + 1) * YT + h] = (gl >= 0 && gl < 1022) ? f2bf(v) : (uint16_t)0;
      } else if constexpr (PHASE == 3) {
        if (il >= 1 && il < 66) yout[(il + 1) * YT + h] = (gl >= 0 && gl < 1023) ? f2bf(v) : (uint16_t)0;
      } else {
        if (il >= 2 && il < 66) Xg[(size_t)gl * 64 + h] = f2bf(v);
      }
    }
  }
}

__global__ __launch_bounds__(256, 6) void conv_stack_k(
    const float* __restrict__ inp, const float* __restrict__ w1p,
    const float* __restrict__ F,
    const uint16_t* __restrict__ W2a, const uint16_t* __restrict__ T1a,
    const uint16_t* __restrict__ T2a,
    uint16_t* __restrict__ X)
{
  __shared__ __align__(16) uint16_t yTA[NROW * YT];
  __shared__ __align__(16) uint16_t yTB[NROW * YT];
  __shared__ float xs[6][YT];
  const int tid  = threadIdx.x;
  const int lane = tid & 63;
  const int wv   = tid >> 6;
  const int t    = blockIdx.y;
  const int l0   = blockIdx.x * 64;

  for (int i = tid; i < 6 * YT; i += 256) {
    int c = i % 6, il = i / 6;
    int gl = l0 - 2 + il;
    float v = 0.f;
    if (gl >= 0 && gl < 1024) v = inp[(size_t)t * 6144 + (size_t)gl * 6 + c];
    xs[c][il] = v;
  }

  // ---- phase 1 (VALU): y1 = relu(bn1(conv1(x))), write yTA rows 1..67
  {
    const int h = lane;
    float wr[12];
#pragma unroll
    for (int i = 0; i < 6; ++i) {
      float2 q = *(const float2*)(w1p + h * 12 + i * 2);
      wr[i * 2] = q.x; wr[i * 2 + 1] = q.y;
    }
    float sc = F[h], tc = F[64 + h];
    __syncthreads();   // xs ready
#pragma unroll 1
    for (int base = wv * 4; base < 67; base += 16) {
      float a0 = 0, a1 = 0, a2 = 0, a3 = 0;
#pragma unroll
      for (int c = 0; c < 6; ++c) {
        float4 v = *(const float4*)&xs[c][base];
        float s4 = xs[c][base + 4];
        float k0 = wr[c * 2], k1 = wr[c * 2 + 1];
        a0 += v.x * k0 + v.y * k1;
        a1 += v.y * k0 + v.z * k1;
        a2 += v.z * k0 + v.w * k1;
        a3 += v.w * k0 + s4 * k1;
      }
      float r[4] = {a0, a1, a2, a3};
#pragma unroll
      for (int j = 0; j < 4; ++j) {
        int il = base + j;
        if (il < 67) {
          int gl = l0 - 2 + il;
          yTA[(il + 1) * YT + h] =
              (gl >= 0 && gl < 1023) ? f2bf(fmaxf(r[j] * sc + tc, 0.f)) : (uint16_t)0;
        }
      }
    }
  }
  __syncthreads();

  mfma_phase<2>(yTA, yTB, nullptr, W2a, F + 128, F + 192, lane, wv, l0);
  __syncthreads();
  mfma_phase<3>(yTB, yTA, nullptr, T1a, F + 256, F + 320, lane, wv, l0);
  __syncthreads();
  mfma_phase<4>(yTA, nullptr, X + (size_t)(t + 1) * 65536, T2a,
                F + 384, F + 448, lane, wv, l0);
}

// ============================== LSTM v15 ====================================
// 256 blocks x 320 threads: waves 0-3 compute (4 rows, 1 cell/lane), wave 4
// projection. 8 barriers per 8-step batch in BOTH paths.
#define HSTR 72

#define BARRIER() do {                                                         \
    asm volatile("s_waitcnt lgkmcnt(0)" ::: "memory");                         \
    __builtin_amdgcn_s_barrier();                                              \
    asm volatile("" ::: "memory");                                             \
  } while (0)

// compute step; K_ literal 0..7 (hh slot), DG literal dribble gate
#define LSTM_STEP(T_, K_, AXC, DG, XD, AXN) do {                               \
    bf16x8 hf0_ = *(const bf16x8*)&hh[((K_) + 7) & 7][(lm >> 2) * HSTR + lq * 8];      \
    bf16x8 hf1_ = *(const bf16x8*)&hh[((K_) + 7) & 7][(lm >> 2) * HSTR + 32 + lq * 8]; \
    f32x4 z0_ = MFMA16(hf1_, bfr[0][3], MFMA16(hf0_, bfr[0][2], AXC[0]));      \
    f32x4 z1_ = MFMA16(hf1_, bfr[1][3], MFMA16(hf0_, bfr[1][2], AXC[1]));      \
    f32x4 z2_ = MFMA16(hf1_, bfr[2][3], MFMA16(hf0_, bfr[2][2], AXC[2]));      \
    f32x4 z3_ = MFMA16(hf1_, bfr[3][3], MFMA16(hf0_, bfr[3][2], AXC[3]));      \
    float ii_ = fsig2(z0_[(K_) & 3]);                                          \
    float ff_ = fsig2(z1_[(K_) & 3]);                                          \
    float gg_ = ftanh2(z2_[(K_) & 3]);                                         \
    float oo_ = fsig2(z3_[(K_) & 3]);                                          \
    creg  = ff_ * creg + ii_ * gg_;                                            \
    float th_ = 1.f - 2.f * frcp(1.f + __builtin_amdgcn_exp2f(creg * 2.88539008177793f)); \
    hprev = oo_ * th_;                                                         \
    uint32_t hw_;                                                              \
    asm("v_cvt_pk_bf16_f32 %0, %1, %2" : "=v"(hw_) : "v"(hprev), "v"(0.f));    \
    hh[(K_)][lq * HSTR + hcol] = (uint16_t)hw_;                                \
    AXN[DG] = MFMA16(XD[1], bfr[DG][1], MFMA16(XD[0], bfr[DG][0], seeds[DG])); \
    BARRIER();                                                                 \
  } while (0)

__global__ __launch_bounds__(320) void lstm_k(
    const float* __restrict__ h0p, const float* __restrict__ c0p,
    const float* __restrict__ wihp, const float* __restrict__ whhp,
    const float* __restrict__ bihp, const float* __restrict__ bhhp,
    const float* __restrict__ owp, const float* __restrict__ obp,
    uint16_t* __restrict__ Xb, float* __restrict__ outp)
{
  __shared__ __align__(16) uint16_t hh[8][4 * HSTR];   // 8-deep h history
  const int tid  = threadIdx.x;
  const int lane = tid & 63;
  const int wv   = tid >> 6;                // 0..4
  const int lm   = lane & 15;
  const int lq   = lane >> 4;
  const int l0   = blockIdx.x << 2;         // 4 batch rows per block
  const f32x4 Z4 = {0.f, 0.f, 0.f, 0.f};

  // stage h0 -> hh[7] ("step -1")
  if (tid < 256) {
    int row = tid >> 6, col = tid & 63;
    hh[7][row * HSTR + col] = f2bf(h0p[(size_t)(l0 + row) * 64 + col]);
  }
  __syncthreads();

  if (wv == 4) {
    // ---------------- projection wave ----------------
    bf16x8 owf0 = {0, 0, 0, 0, 0, 0, 0, 0}, owf1 = {0, 0, 0, 0, 0, 0, 0, 0};
    if (lm == 0) {
#pragma unroll
      for (int j = 0; j < 8; ++j) {
        owf0[j] = (short)f2bf(owp[lq * 8 + j]);
        owf1[j] = (short)f2bf(owp[32 + lq * 8 + j]);
      }
    }
    float obv = obp[0];
#pragma unroll 1
    for (int t0 = 0; t0 < 512; t0 += 8) {
      if (t0 > 0) {   // steps t0-4..t0-1 live in slots 4..7
        bf16x8 pa0 = *(const bf16x8*)&hh[4 + (lm & 3)][(lm >> 2) * HSTR + lq * 8];
        bf16x8 pa1 = *(const bf16x8*)&hh[4 + (lm & 3)][(lm >> 2) * HSTR + 32 + lq * 8];
        f32x4 pr = MFMA16(pa1, owf1, MFMA16(pa0, owf0, Z4));
        if (lm == 0) {
          outp[(size_t)(t0 - 4) * 1024 + l0 + lq] = pr[0] + obv;
          outp[(size_t)(t0 - 3) * 1024 + l0 + lq] = pr[1] + obv;
          outp[(size_t)(t0 - 2) * 1024 + l0 + lq] = pr[2] + obv;
          outp[(size_t)(t0 - 1) * 1024 + l0 + lq] = pr[3] + obv;
        }
      }
      BARRIER(); BARRIER(); BARRIER(); BARRIER();   // steps t0+0..t0+3
      {             // steps t0+0..t0+3 now live in slots 0..3
        bf16x8 pa0 = *(const bf16x8*)&hh[(lm & 3)][(lm >> 2) * HSTR + lq * 8];
        bf16x8 pa1 = *(const bf16x8*)&hh[(lm & 3)][(lm >> 2) * HSTR + 32 + lq * 8];
        f32x4 pr = MFMA16(pa1, owf1, MFMA16(pa0, owf0, Z4));
        if (lm == 0) {
          outp[(size_t)(t0 + 0) * 1024 + l0 + lq] = pr[0] + obv;
          outp[(size_t)(t0 + 1) * 1024 + l0 + lq] = pr[1] + obv;
          outp[(size_t)(t0 + 2) * 1024 + l0 + lq] = pr[2] + obv;
          outp[(size_t)(t0 + 3) * 1024 + l0 + lq] = pr[3] + obv;
        }
      }
      BARRIER(); BARRIER(); BARRIER(); BARRIER();   // steps t0+4..t0+7
    }
    // post-loop: steps 508-511 from slots 4-7
    {
      bf16x8 pa0 = *(const bf16x8*)&hh[4 + (lm & 3)][(lm >> 2) * HSTR + lq * 8];
      bf16x8 pa1 = *(const bf16x8*)&hh[4 + (lm & 3)][(lm >> 2) * HSTR + 32 + lq * 8];
      f32x4 pr = MFMA16(pa1, owf1, MFMA16(pa0, owf0, Z4));
      if (lm == 0) {
        outp[(size_t)508 * 1024 + l0 + lq] = pr[0] + obv;
        outp[(size_t)509 * 1024 + l0 + lq] = pr[1] + obv;
        outp[(size_t)510 * 1024 + l0 + lq] = pr[2] + obv;
        outp[(size_t)511 * 1024 + l0 + lq] = pr[3] + obv;
      }
    }
    return;
  }

  // ---------------- compute waves (0-3) ----------------
  const int hcol = (wv << 4) | lm;
  const float L2E = 1.44269504088896340736f;

  // B weights, pre-scaled: i,f,o x log2e ; g x 2*log2e
  bf16x8 bfr[4][4];
#pragma unroll
  for (int nt = 0; nt < 4; ++nt) {
    float sg = (nt == 2) ? 2.f * L2E : L2E;
    int n = nt * 64 + hcol;
#pragma unroll
    for (int kc = 0; kc < 4; ++kc) {
      int k0 = kc * 32 + lq * 8;
      const float* src = (k0 < 64) ? (wihp + (size_t)n * 64 + k0)
                                   : (whhp + (size_t)n * 64 + (k0 - 64));
      bf16x8 f;
#pragma unroll
      for (int j = 0; j < 8; ++j) f[j] = (short)f2bf(src[j] * sg);
      bfr[nt][kc] = f;
    }
  }
  float bi0 = (bihp[hcol]       + bhhp[hcol])       * L2E;
  float bi1 = (bihp[64 + hcol]  + bhhp[64 + hcol])  * L2E;
  float bi2 = (bihp[128 + hcol] + bhhp[128 + hcol]) * 2.f * L2E;
  float bi3 = (bihp[192 + hcol] + bhhp[192 + hcol]) * L2E;
  f32x4 seeds[4];
  seeds[0] = f32x4{bi0, bi0, bi0, bi0};
  seeds[1] = f32x4{bi1, bi1, bi1, bi1};
  seeds[2] = f32x4{bi2, bi2, bi2, bi2};
  seeds[3] = f32x4{bi3, bi3, bi3, bi3};

  // one cell per lane: (batch row lq, h-col hcol)
  float creg  = c0p[(size_t)(l0 + lq) * 64 + hcol];
  float hprev = 0.f;

  // running x pointers: batch t0 reads slots t0+1..t0+4
  const uint16_t* pA = Xb + (size_t)(1 + (lm & 3)) * 65536
                     + (size_t)(l0 + (lm >> 2)) * 64 + lq * 8;
  const uint16_t* pB = pA + (size_t)4 * 65536;
  bf16x8 xA[2], xB[2];
  xA[0] = *(const bf16x8*)pA; xA[1] = *(const bf16x8*)(pA + 32);
  pA += (size_t)8 * 65536;
  xB[0] = *(const bf16x8*)pB; xB[1] = *(const bf16x8*)(pB + 32);
  pB += (size_t)8 * 65536;

  f32x4 axA[4], axB[4];
#pragma unroll
  for (int g = 0; g < 4; ++g)
    axA[g] = MFMA16(xA[1], bfr[g][1], MFMA16(xA[0], bfr[g][0], seeds[g]));

#pragma unroll 1
  for (int t0 = 0; t0 < 512; t0 += 8) {
    if (t0 + 8 < 512) {          // xA <- batch t0+8 (dribbled at steps 4-7)
      xA[0] = *(const bf16x8*)pA; xA[1] = *(const bf16x8*)(pA + 32);
      pA += (size_t)8 * 65536;
    }
    LSTM_STEP(t0 + 0, 0, axA, 0, xB, axB);
    LSTM_STEP(t0 + 1, 1, axA, 1, xB, axB);
    LSTM_STEP(t0 + 2, 2, axA, 2, xB, axB);
    LSTM_STEP(t0 + 3, 3, axA, 3, xB, axB);
    if (t0 + 12 < 512) {         // xB <- batch t0+12 (dribbled next iter 0-3)
      xB[0] = *(const bf16x8*)pB; xB[1] = *(const bf16x8*)(pB + 32);
      pB += (size_t)8 * 65536;
    }
    LSTM_STEP(t0 + 4, 4, axB, 0, xA, axA);
    LSTM_STEP(t0 + 5, 5, axB, 1, xA, axA);
    LSTM_STEP(t0 + 6, 6, axB, 2, xA, axA);
    LSTM_STEP(t0 + 7, 7, axB, 3, xA, axA);
  }

  // hT at out+524288, cT at out+589824 (fp32)
  outp[524288 + (size_t)(l0 + lq) * 64 + hcol] = hprev;
  outp[589824 + (size_t)(l0 + lq) * 64 + hcol] = creg;
}

// ============================== launch =====================================
extern "C" void kernel_launch(void* const* d_in, const int* in_sizes, int n_in,
                              void* d_out, int out_size, void* d_ws, size_t ws_size,
                              hipStream_t stream)
{
  (void)in_sizes; (void)n_in; (void)out_size;
  if (ws_size < (size_t)513 * 65536 * 2) return;   // ws guard

  const float* inp = (const float*)d_in[0];
  const float* h0p = (const float*)d_in[1];
  const float* c0p = (const float*)d_in[2];
  const float* w1  = (const float*)d_in[3];
  const float* b1  = (const float*)d_in[4];
  const float* g1  = (const float*)d_in[5];
  const float* be1 = (const float*)d_in[6];
  const float* m1  = (const float*)d_in[7];
  const float* v1  = (const float*)d_in[8];
  const float* w2  = (const float*)d_in[9];
  const float* b2  = (const float*)d_in[10];
  const float* g2  = (const float*)d_in[11];
  const float* be2 = (const float*)d_in[12];
  const float* m2  = (const float*)d_in[13];
  const float* v2  = (const float*)d_in[14];
  const float* tw1 = (const float*)d_in[15];
  const float* tb1 = (const float*)d_in[16];
  const float* g3  = (const float*)d_in[17];
  const float* be3 = (const float*)d_in[18];
  const float* m3  = (const float*)d_in[19];
  const float* v3  = (const float*)d_in[20];
  const float* tw2 = (const float*)d_in[21];
  const float* tb2 = (const float*)d_in[22];
  const float* wih = (const float*)d_in[23];
  const float* whh = (const float*)d_in[24];
  const float* bih = (const float*)d_in[25];
  const float* bhh = (const float*)d_in[26];
  const float* ow  = (const float*)d_in[27];
  const float* ob  = (const float*)d_in[28];

  uint16_t* Xb   = (uint16_t*)d_ws;
  float*    outp = (float*)d_out;

  // slot 0 of Xb: W2a[0,8192) T1a[8192,16384) T2a[16384,24576) F(f32 x512)
  const uint16_t* W2a = Xb;
  const uint16_t* T1a = Xb + 8192;
  const uint16_t* T2a = Xb + 16384;
  const float*    F   = (const float*)(Xb + 24576);

  prep_k<<<98, 256, 0, stream>>>(w2, tw1, tw2,
                                 g1, be1, m1, v1, b1,
                                 g2, be2, m2, v2, b2,
                                 g3, be3, m3, v3, tb1, tb2, Xb);
  conv_stack_k<<<dim3(16, 512), 256, 0, stream>>>(inp, w1, F, W2a, T1a, T2a, Xb);
  lstm_k<<<256, 320, 0, stream>>>(h0p, c0p, wih, whh, bih, bhh, ow, ob, Xb, outp);
}

// Round 16
// 206.566 us; speedup vs baseline: 1.1649x; 1.0126x over previous
//
#include <hip/hip_runtime.h>
#include <hip/hip_bf16.h>
#include <stdint.h>

// ---------------------------------------------------------------------------
// CNNLSTM: conv stack (ALL 4 phases MFMA) -> LSTM(T=512,batch=1024,H=64) -> proj
// v16 (= v15 + conv phase-1 on MFMA):
//  prep_k: conv weights W1/W2/T1/T2 -> bf16 A-fragment layout in ws slot 0
//          (W1a zero-padded K=12->32); BN scale/shift fused into F[].
//  conv:   phase 1 = 1 MFMA per 16-col tile vs ~240 scalar FMA/thread.
//          x staged as bf16 B-tile xsb[il][k=2c+d] (zero-filled, masked rows
//          garbage-tolerant: il>=67 outputs store-masked, per-column D).
//  LSTM:   v15 unchanged (320 thr: 4 compute waves + 1 projection wave).
// ws layout: slot 0 = W2a[0,8192) T1a[8192,16384) T2a[16384,24576)
//            F f32 [24576,25600) W1a [25600,27648); slots 1..512 = x_t.
// ---------------------------------------------------------------------------

typedef __attribute__((ext_vector_type(8))) short bf16x8;
typedef __attribute__((ext_vector_type(4))) float f32x4;

__device__ __forceinline__ uint16_t f2bf(float f) {
  union { float f; uint32_t i; } v; v.f = f;
  return (uint16_t)((v.i + 0x7FFFu + ((v.i >> 16) & 1u)) >> 16);  // RNE
}
__device__ __forceinline__ float frcp(float x) { return __builtin_amdgcn_rcpf(x); }
// pre-scaled variants: z already multiplied by log2e (sig) / 2*log2e (tanh)
__device__ __forceinline__ float fsig2(float z)  { return frcp(1.f + __builtin_amdgcn_exp2f(-z)); }
__device__ __forceinline__ float ftanh2(float z) { return 1.f - 2.f * frcp(1.f + __builtin_amdgcn_exp2f(z)); }

#define MFMA16(a, b, c) __builtin_amdgcn_mfma_f32_16x16x32_bf16(a, b, c, 0, 0, 0)

// ============================ prep kernel ===================================
__global__ __launch_bounds__(256) void prep_k(
    const float* __restrict__ w1p,
    const float* __restrict__ w2p, const float* __restrict__ t1p,
    const float* __restrict__ t2p,
    const float* __restrict__ g1, const float* __restrict__ be1,
    const float* __restrict__ m1, const float* __restrict__ v1,
    const float* __restrict__ b1,
    const float* __restrict__ g2, const float* __restrict__ be2,
    const float* __restrict__ m2, const float* __restrict__ v2,
    const float* __restrict__ b2,
    const float* __restrict__ g3, const float* __restrict__ be3,
    const float* __restrict__ m3, const float* __restrict__ v3,
    const float* __restrict__ tb1, const float* __restrict__ tb2,
    uint16_t* __restrict__ W)
{
  int idx = blockIdx.x * 256 + threadIdx.x;
  if (idx < 8192) {
    int h = idx >> 7, k = idx & 127;
    W[idx] = f2bf(w2p[h * 128 + (k & 63) * 2 + (k >> 6)]);
  } else if (idx < 16384) {
    int i = idx - 8192; int h = i >> 7, k = i & 127;
    W[idx] = f2bf(t1p[(k & 63) * 128 + h * 2 + (k >> 6)]);
  } else if (idx < 24576) {
    int i = idx - 16384; int h = i >> 7, k = i & 127;
    W[idx] = f2bf(t2p[(k & 63) * 128 + h * 2 + (k >> 6)]);
  } else if (idx < 25088) {
    int i = idx - 24576;            // 0..511
    float* F = (float*)(W + 24576);
    int h = i & 63, sel = i >> 6;
    float val;
    if (sel == 0)      val = g1[h] * __builtin_amdgcn_rsqf(v1[h] + 1e-5f);
    else if (sel == 1) { float s = g1[h] * __builtin_amdgcn_rsqf(v1[h] + 1e-5f);
                         val = (b1[h] - m1[h]) * s + be1[h]; }
    else if (sel == 2) val = g2[h] * __builtin_amdgcn_rsqf(v2[h] + 1e-5f);
    else if (sel == 3) { float s = g2[h] * __builtin_amdgcn_rsqf(v2[h] + 1e-5f);
                         val = (b2[h] - m2[h]) * s + be2[h]; }
    else if (sel == 4) val = g3[h] * __builtin_amdgcn_rsqf(v3[h] + 1e-5f);
    else if (sel == 5) { float s = g3[h] * __builtin_amdgcn_rsqf(v3[h] + 1e-5f);
                         val = (tb1[h] - m3[h]) * s + be3[h]; }
    else if (sel == 6) val = 1.0f;
    else               val = tb2[h];
    F[i] = val;
  } else if (idx >= 25600 && idx < 27648) {
    // W1a[h][k=2c+d], k<12 real, else 0  (w1p layout [h][c][d] = h*12+k)
    int i = idx - 25600; int h = i >> 5, k = i & 31;
    W[idx] = (k < 12) ? f2bf(w1p[h * 12 + k]) : (uint16_t)0;
  }
}

// ============================ conv stack ===================================
#define YT   72
#define NROW 84
#define XST  40    // xsb row stride (uint16)

template<int PHASE>
__device__ __forceinline__ void mfma_phase(
    const uint16_t* yin, uint16_t* yout, uint16_t* Xg,
    const uint16_t* __restrict__ wAg,          // global A-layout [64][128]
    const float* __restrict__ p_sc, const float* __restrict__ p_tc,
    int lane, int wv, int l0)
{
  const int m0 = wv * 16;
  const int lm = lane & 15, lq = lane >> 4;
  bf16x8 af[4];
#pragma unroll
  for (int kc = 0; kc < 4; ++kc)
    af[kc] = *(const bf16x8*)&wAg[(m0 + lm) * 128 + kc * 32 + lq * 8];
  float scr[4], tcr[4];
#pragma unroll
  for (int r = 0; r < 4; ++r) {
    int hr = m0 + lq * 4 + r;
    scr[r] = p_sc[hr]; tcr[r] = p_tc[hr];
  }
  const f32x4 Z = {0.f, 0.f, 0.f, 0.f};
#pragma unroll
  for (int nt = 0; nt < 5; ++nt) {
    f32x4 acc = Z;
#pragma unroll
    for (int kc = 0; kc < 4; ++kc) {
      int half = kc >> 1;
      int rT = nt * 16 + lm + 1 + (PHASE == 2 ? half : -half);
      bf16x8 bf_ = *(const bf16x8*)&yin[rT * YT + (kc & 1) * 32 + lq * 8];
      acc = MFMA16(af[kc], bf_, acc);
    }
    int il = nt * 16 + lm;
    int gl = l0 - 2 + il;
#pragma unroll
    for (int r = 0; r < 4; ++r) {
      int h = m0 + lq * 4 + r;
      float v = fmaxf(acc[r] * scr[r] + tcr[r], 0.f);
      if constexpr (PHASE == 2) {
        if (il < 66) yout[(il + 1) * YT + h] = (gl >= 0 && gl < 1022) ? f2bf(v) : (uint16_t)0;
      } else if constexpr (PHASE == 3) {
        if (il >= 1 && il < 66) yout[(il + 1) * YT + h] = (gl >= 0 && gl < 1023) ? f2bf(v) : (uint16_t)0;
      } else {
        if (il >= 2 && il < 66) Xg[(size_t)gl * 64 + h] = f2bf(v);
      }
    }
  }
}

__global__ __launch_bounds__(256, 6) void conv_stack_k(
    const float* __restrict__ inp,
    const float* __restrict__ F,
    const uint16_t* __restrict__ W1a, const uint16_t* __restrict__ W2a,
    const uint16_t* __restrict__ T1a, const uint16_t* __restrict__ T2a,
    uint16_t* __restrict__ X)
{
  __shared__ __align__(16) uint16_t yTA[NROW * YT];
  __shared__ __align__(16) uint16_t yTB[NROW * YT];
  __shared__ __align__(16) uint16_t xsb[80 * XST];  // phase-1 B tile [il][k]
  const int tid  = threadIdx.x;
  const int lane = tid & 63;
  const int wv   = tid >> 6;
  const int t    = blockIdx.y;
  const int l0   = blockIdx.x * 64;
  const int lm   = lane & 15, lq = lane >> 4;
  const f32x4 Z = {0.f, 0.f, 0.f, 0.f};

  // zero xsb rows 0..71 (valid-output region; rows 72..79 garbage-tolerated)
  for (int i = tid; i < 72 * XST / 8; i += 256)
    ((int4*)xsb)[i] = int4{0, 0, 0, 0};
  __syncthreads();

  // stage x -> xsb[il][2c+d] (bf16): element (c, il) feeds d=0 of row il and
  // d=1 of row il-1. gl outside [0,1024) stays zero. Coalesced global reads.
  for (int i = tid; i < 432; i += 256) {
    int c = i % 6, il = i / 6;
    int gl = l0 - 2 + il;
    if (gl >= 0 && gl < 1024) {
      uint16_t v = f2bf(inp[(size_t)t * 6144 + (size_t)gl * 6 + c]);
      xsb[il * XST + 2 * c] = v;
      if (il > 0) xsb[(il - 1) * XST + 2 * c + 1] = v;
    }
  }
  __syncthreads();

  // ---- phase 1 (MFMA): y1 = relu(bn1(conv1(x))), write yTA rows 1..67
  {
    const int m0 = wv * 16;
    bf16x8 af = *(const bf16x8*)&W1a[(m0 + lm) * 32 + lq * 8];
    float scr[4], tcr[4];
#pragma unroll
    for (int r = 0; r < 4; ++r) {
      int hr = m0 + lq * 4 + r;
      scr[r] = F[hr]; tcr[r] = F[64 + hr];
    }
#pragma unroll
    for (int nt = 0; nt < 5; ++nt) {
      bf16x8 bf_ = *(const bf16x8*)&xsb[(nt * 16 + lm) * XST + lq * 8];
      f32x4 acc = MFMA16(af, bf_, Z);
      int il = nt * 16 + lm;
      int gl = l0 - 2 + il;
#pragma unroll
      for (int r = 0; r < 4; ++r) {
        int h = m0 + lq * 4 + r;
        float v = fmaxf(acc[r] * scr[r] + tcr[r], 0.f);
        if (il < 67)
          yTA[(il + 1) * YT + h] =
              (gl >= 0 && gl < 1023) ? f2bf(v) : (uint16_t)0;
      }
    }
  }
  __syncthreads();

  mfma_phase<2>(yTA, yTB, nullptr, W2a, F + 128, F + 192, lane, wv, l0);
  __syncthreads();
  mfma_phase<3>(yTB, yTA, nullptr, T1a, F + 256, F + 320, lane, wv, l0);
  __syncthreads();
  mfma_phase<4>(yTA, nullptr, X + (size_t)(t + 1) * 65536, T2a,
                F + 384, F + 448, lane, wv, l0);
}

// ============================== LSTM v15 (unchanged) ========================
// 256 blocks x 320 threads: waves 0-3 compute (4 rows, 1 cell/lane), wave 4
// projection. 8 barriers per 8-step batch in BOTH paths.
#define HSTR 72

#define BARRIER() do {                                                         \
    asm volatile("s_waitcnt lgkmcnt(0)" ::: "memory");                         \
    __builtin_amdgcn_s_barrier();                                              \
    asm volatile("" ::: "memory");                                             \
  } while (0)

// compute step; K_ literal 0..7 (hh slot), DG literal dribble gate
#define LSTM_STEP(T_, K_, AXC, DG, XD, AXN) do {                               \
    bf16x8 hf0_ = *(const bf16x8*)&hh[((K_) + 7) & 7][(lm >> 2) * HSTR + lq * 8];      \
    bf16x8 hf1_ = *(const bf16x8*)&hh[((K_) + 7) & 7][(lm >> 2) * HSTR + 32 + lq * 8]; \
    f32x4 z0_ = MFMA16(hf1_, bfr[0][3], MFMA16(hf0_, bfr[0][2], AXC[0]));      \
    f32x4 z1_ = MFMA16(hf1_, bfr[1][3], MFMA16(hf0_, bfr[1][2], AXC[1]));      \
    f32x4 z2_ = MFMA16(hf1_, bfr[2][3], MFMA16(hf0_, bfr[2][2], AXC[2]));      \
    f32x4 z3_ = MFMA16(hf1_, bfr[3][3], MFMA16(hf0_, bfr[3][2], AXC[3]));      \
    float ii_ = fsig2(z0_[(K_) & 3]);                                          \
    float ff_ = fsig2(z1_[(K_) & 3]);                                          \
    float gg_ = ftanh2(z2_[(K_) & 3]);                                         \
    float oo_ = fsig2(z3_[(K_) & 3]);                                          \
    creg  = ff_ * creg + ii_ * gg_;                                            \
    float th_ = 1.f - 2.f * frcp(1.f + __builtin_amdgcn_exp2f(creg * 2.88539008177793f)); \
    hprev = oo_ * th_;                                                         \
    uint32_t hw_;                                                              \
    asm("v_cvt_pk_bf16_f32 %0, %1, %2" : "=v"(hw_) : "v"(hprev), "v"(0.f));    \
    hh[(K_)][lq * HSTR + hcol] = (uint16_t)hw_;                                \
    AXN[DG] = MFMA16(XD[1], bfr[DG][1], MFMA16(XD[0], bfr[DG][0], seeds[DG])); \
    BARRIER();                                                                 \
  } while (0)

__global__ __launch_bounds__(320) void lstm_k(
    const float* __restrict__ h0p, const float* __restrict__ c0p,
    const float* __restrict__ wihp, const float* __restrict__ whhp,
    const float* __restrict__ bihp, const float* __restrict__ bhhp,
    const float* __restrict__ owp, const float* __restrict__ obp,
    uint16_t* __restrict__ Xb, float* __restrict__ outp)
{
  __shared__ __align__(16) uint16_t hh[8][4 * HSTR];   // 8-deep h history
  const int tid  = threadIdx.x;
  const int lane = tid & 63;
  const int wv   = tid >> 6;                // 0..4
  const int lm   = lane & 15;
  const int lq   = lane >> 4;
  const int l0   = blockIdx.x << 2;         // 4 batch rows per block
  const f32x4 Z4 = {0.f, 0.f, 0.f, 0.f};

  // stage h0 -> hh[7] ("step -1")
  if (tid < 256) {
    int row = tid >> 6, col = tid & 63;
    hh[7][row * HSTR + col] = f2bf(h0p[(size_t)(l0 + row) * 64 + col]);
  }
  __syncthreads();

  if (wv == 4) {
    // ---------------- projection wave ----------------
    bf16x8 owf0 = {0, 0, 0, 0, 0, 0, 0, 0}, owf1 = {0, 0, 0, 0, 0, 0, 0, 0};
    if (lm == 0) {
#pragma unroll
      for (int j = 0; j < 8; ++j) {
        owf0[j] = (short)f2bf(owp[lq * 8 + j]);
        owf1[j] = (short)f2bf(owp[32 + lq * 8 + j]);
      }
    }
    float obv = obp[0];
#pragma unroll 1
    for (int t0 = 0; t0 < 512; t0 += 8) {
      if (t0 > 0) {   // steps t0-4..t0-1 live in slots 4..7
        bf16x8 pa0 = *(const bf16x8*)&hh[4 + (lm & 3)][(lm >> 2) * HSTR + lq * 8];
        bf16x8 pa1 = *(const bf16x8*)&hh[4 + (lm & 3)][(lm >> 2) * HSTR + 32 + lq * 8];
        f32x4 pr = MFMA16(pa1, owf1, MFMA16(pa0, owf0, Z4));
        if (lm == 0) {
          outp[(size_t)(t0 - 4) * 1024 + l0 + lq] = pr[0] + obv;
          outp[(size_t)(t0 - 3) * 1024 + l0 + lq] = pr[1] + obv;
          outp[(size_t)(t0 - 2) * 1024 + l0 + lq] = pr[2] + obv;
          outp[(size_t)(t0 - 1) * 1024 + l0 + lq] = pr[3] + obv;
        }
      }
      BARRIER(); BARRIER(); BARRIER(); BARRIER();   // steps t0+0..t0+3
      {             // steps t0+0..t0+3 now live in slots 0..3
        bf16x8 pa0 = *(const bf16x8*)&hh[(lm & 3)][(lm >> 2) * HSTR + lq * 8];
        bf16x8 pa1 = *(const bf16x8*)&hh[(lm & 3)][(lm >> 2) * HSTR + 32 + lq * 8];
        f32x4 pr = MFMA16(pa1, owf1, MFMA16(pa0, owf0, Z4));
        if (lm == 0) {
          outp[(size_t)(t0 + 0) * 1024 + l0 + lq] = pr[0] + obv;
          outp[(size_t)(t0 + 1) * 1024 + l0 + lq] = pr[1] + obv;
          outp[(size_t)(t0 + 2) * 1024 + l0 + lq] = pr[2] + obv;
          outp[(size_t)(t0 + 3) * 1024 + l0 + lq] = pr[3] + obv;
        }
      }
      BARRIER(); BARRIER(); BARRIER(); BARRIER();   // steps t0+4..t0+7
    }
    // post-loop: steps 508-511 from slots 4-7
    {
      bf16x8 pa0 = *(const bf16x8*)&hh[4 + (lm & 3)][(lm >> 2) * HSTR + lq * 8];
      bf16x8 pa1 = *(const bf16x8*)&hh[4 + (lm & 3)][(lm >> 2) * HSTR + 32 + lq * 8];
      f32x4 pr = MFMA16(pa1, owf1, MFMA16(pa0, owf0, Z4));
      if (lm == 0) {
        outp[(size_t)508 * 1024 + l0 + lq] = pr[0] + obv;
        outp[(size_t)509 * 1024 + l0 + lq] = pr[1] + obv;
        outp[(size_t)510 * 1024 + l0 + lq] = pr[2] + obv;
        outp[(size_t)511 * 1024 + l0 + lq] = pr[3] + obv;
      }
    }
    return;
  }

  // ---------------- compute waves (0-3) ----------------
  const int hcol = (wv << 4) | lm;
  const float L2E = 1.44269504088896340736f;

  // B weights, pre-scaled: i,f,o x log2e ; g x 2*log2e
  bf16x8 bfr[4][4];
#pragma unroll
  for (int nt = 0; nt < 4; ++nt) {
    float sg = (nt == 2) ? 2.f * L2E : L2E;
    int n = nt * 64 + hcol;
#pragma unroll
    for (int kc = 0; kc < 4; ++kc) {
      int k0 = kc * 32 + lq * 8;
      const float* src = (k0 < 64) ? (wihp + (size_t)n * 64 + k0)
                                   : (whhp + (size_t)n * 64 + (k0 - 64));
      bf16x8 f;
#pragma unroll
      for (int j = 0; j < 8; ++j) f[j] = (short)f2bf(src[j] * sg);
      bfr[nt][kc] = f;
    }
  }
  float bi0 = (bihp[hcol]       + bhhp[hcol])       * L2E;
  float bi1 = (bihp[64 + hcol]  + bhhp[64 + hcol])  * L2E;
  float bi2 = (bihp[128 + hcol] + bhhp[128 + hcol]) * 2.f * L2E;
  float bi3 = (bihp[192 + hcol] + bhhp[192 + hcol]) * L2E;
  f32x4 seeds[4];
  seeds[0] = f32x4{bi0, bi0, bi0, bi0};
  seeds[1] = f32x4{bi1, bi1, bi1, bi1};
  seeds[2] = f32x4{bi2, bi2, bi2, bi2};
  seeds[3] = f32x4{bi3, bi3, bi3, bi3};

  // one cell per lane: (batch row lq, h-col hcol)
  float creg  = c0p[(size_t)(l0 + lq) * 64 + hcol];
  float hprev = 0.f;

  // running x pointers: batch t0 reads slots t0+1..t0+4
  const uint16_t* pA = Xb + (size_t)(1 + (lm & 3)) * 65536
                     + (size_t)(l0 + (lm >> 2)) * 64 + lq * 8;
  const uint16_t* pB = pA + (size_t)4 * 65536;
  bf16x8 xA[2], xB[2];
  xA[0] = *(const bf16x8*)pA; xA[1] = *(const bf16x8*)(pA + 32);
  pA += (size_t)8 * 65536;
  xB[0] = *(const bf16x8*)pB; xB[1] = *(const bf16x8*)(pB + 32);
  pB += (size_t)8 * 65536;

  f32x4 axA[4], axB[4];
#pragma unroll
  for (int g = 0; g < 4; ++g)
    axA[g] = MFMA16(xA[1], bfr[g][1], MFMA16(xA[0], bfr[g][0], seeds[g]));

#pragma unroll 1
  for (int t0 = 0; t0 < 512; t0 += 8) {
    if (t0 + 8 < 512) {          // xA <- batch t0+8 (dribbled at steps 4-7)
      xA[0] = *(const bf16x8*)pA; xA[1] = *(const bf16x8*)(pA + 32);
      pA += (size_t)8 * 65536;
    }
    LSTM_STEP(t0 + 0, 0, axA, 0, xB, axB);
    LSTM_STEP(t0 + 1, 1, axA, 1, xB, axB);
    LSTM_STEP(t0 + 2, 2, axA, 2, xB, axB);
    LSTM_STEP(t0 + 3, 3, axA, 3, xB, axB);
    if (t0 + 12 < 512) {         // xB <- batch t0+12 (dribbled next iter 0-3)
      xB[0] = *(const bf16x8*)pB; xB[1] = *(const bf16x8*)(pB + 32);
      pB += (size_t)8 * 65536;
    }
    LSTM_STEP(t0 + 4, 4, axB, 0, xA, axA);
    LSTM_STEP(t0 + 5, 5, axB, 1, xA, axA);
    LSTM_STEP(t0 + 6, 6, axB, 2, xA, axA);
    LSTM_STEP(t0 + 7, 7, axB, 3, xA, axA);
  }

  // hT at out+524288, cT at out+589824 (fp32)
  outp[524288 + (size_t)(l0 + lq) * 64 + hcol] = hprev;
  outp[589824 + (size_t)(l0 + lq) * 64 + hcol] = creg;
}

// ============================== launch =====================================
extern "C" void kernel_launch(void* const* d_in, const int* in_sizes, int n_in,
                              void* d_out, int out_size, void* d_ws, size_t ws_size,
                              hipStream_t stream)
{
  (void)in_sizes; (void)n_in; (void)out_size;
  if (ws_size < (size_t)513 * 65536 * 2) return;   // ws guard

  const float* inp = (const float*)d_in[0];
  const float* h0p = (const float*)d_in[1];
  const float* c0p = (const float*)d_in[2];
  const float* w1  = (const float*)d_in[3];
  const float* b1  = (const float*)d_in[4];
  const float* g1  = (const float*)d_in[5];
  const float* be1 = (const float*)d_in[6];
  const float* m1  = (const float*)d_in[7];
  const float* v1  = (const float*)d_in[8];
  const float* w2  = (const float*)d_in[9];
  const float* b2  = (const float*)d_in[10];
  const float* g2  = (const float*)d_in[11];
  const float* be2 = (const float*)d_in[12];
  const float* m2  = (const float*)d_in[13];
  const float* v2  = (const float*)d_in[14];
  const float* tw1 = (const float*)d_in[15];
  const float* tb1 = (const float*)d_in[16];
  const float* g3  = (const float*)d_in[17];
  const float* be3 = (const float*)d_in[18];
  const float* m3  = (const float*)d_in[19];
  const float* v3  = (const float*)d_in[20];
  const float* tw2 = (const float*)d_in[21];
  const float* tb2 = (const float*)d_in[22];
  const float* wih = (const float*)d_in[23];
  const float* whh = (const float*)d_in[24];
  const float* bih = (const float*)d_in[25];
  const float* bhh = (const float*)d_in[26];
  const float* ow  = (const float*)d_in[27];
  const float* ob  = (const float*)d_in[28];

  uint16_t* Xb   = (uint16_t*)d_ws;
  float*    outp = (float*)d_out;

  // slot 0: W2a[0,8192) T1a[8192,16384) T2a[16384,24576) F[24576,25600) W1a[25600,27648)
  const uint16_t* W2a = Xb;
  const uint16_t* T1a = Xb + 8192;
  const uint16_t* T2a = Xb + 16384;
  const float*    F   = (const float*)(Xb + 24576);
  const uint16_t* W1a = Xb + 25600;

  prep_k<<<108, 256, 0, stream>>>(w1, w2, tw1, tw2,
                                  g1, be1, m1, v1, b1,
                                  g2, be2, m2, v2, b2,
                                  g3, be3, m3, v3, tb1, tb2, Xb);
  conv_stack_k<<<dim3(16, 512), 256, 0, stream>>>(inp, F, W1a, W2a, T1a, T2a, Xb);
  lstm_k<<<256, 320, 0, stream>>>(h0p, c0p, wih, whh, bih, bhh, ow, ob, Xb, outp);
}

// Round 17
// 204.115 us; speedup vs baseline: 1.1789x; 1.0120x over previous
//
#include <hip/hip_runtime.h>
#include <hip/hip_bf16.h>
#include <stdint.h>

// ---------------------------------------------------------------------------
// CNNLSTM: conv stack (ALL 4 phases MFMA) -> LSTM(T=512,batch=1024,H=64) -> proj
// v17 (= v16 + packed conv epilogues):
//  conv epilogue: per nt-group the 4 outputs share il/gl (uniform mask) and
//  are contiguous in h -> 2x v_cvt_pk_bf16_f32 (HW RNE) + uniform zero-select
//  + 2x b32 LDS writes (phase 4: one uint2 global store). Replaces per-elem
//  software-RNE f2bf + 4 scalar stores (~36 ops -> ~14 per group).
//  LSTM: v15 unchanged (320 thr: 4 compute waves + 1 projection wave).
// ws layout: slot 0 = W2a[0,8192) T1a[8192,16384) T2a[16384,24576)
//            F f32 [24576,25600) W1a [25600,27648); slots 1..512 = x_t.
// ---------------------------------------------------------------------------

typedef __attribute__((ext_vector_type(8))) short bf16x8;
typedef __attribute__((ext_vector_type(4))) float f32x4;

__device__ __forceinline__ uint16_t f2bf(float f) {
  union { float f; uint32_t i; } v; v.f = f;
  return (uint16_t)((v.i + 0x7FFFu + ((v.i >> 16) & 1u)) >> 16);  // RNE
}
__device__ __forceinline__ uint32_t cvtpk(float lo, float hi) {
  uint32_t r;
  asm("v_cvt_pk_bf16_f32 %0, %1, %2" : "=v"(r) : "v"(lo), "v"(hi));
  return r;
}
__device__ __forceinline__ float frcp(float x) { return __builtin_amdgcn_rcpf(x); }
// pre-scaled variants: z already multiplied by log2e (sig) / 2*log2e (tanh)
__device__ __forceinline__ float fsig2(float z)  { return frcp(1.f + __builtin_amdgcn_exp2f(-z)); }
__device__ __forceinline__ float ftanh2(float z) { return 1.f - 2.f * frcp(1.f + __builtin_amdgcn_exp2f(z)); }

#define MFMA16(a, b, c) __builtin_amdgcn_mfma_f32_16x16x32_bf16(a, b, c, 0, 0, 0)

// ============================ prep kernel ===================================
__global__ __launch_bounds__(256) void prep_k(
    const float* __restrict__ w1p,
    const float* __restrict__ w2p, const float* __restrict__ t1p,
    const float* __restrict__ t2p,
    const float* __restrict__ g1, const float* __restrict__ be1,
    const float* __restrict__ m1, const float* __restrict__ v1,
    const float* __restrict__ b1,
    const float* __restrict__ g2, const float* __restrict__ be2,
    const float* __restrict__ m2, const float* __restrict__ v2,
    const float* __restrict__ b2,
    const float* __restrict__ g3, const float* __restrict__ be3,
    const float* __restrict__ m3, const float* __restrict__ v3,
    const float* __restrict__ tb1, const float* __restrict__ tb2,
    uint16_t* __restrict__ W)
{
  int idx = blockIdx.x * 256 + threadIdx.x;
  if (idx < 8192) {
    int h = idx >> 7, k = idx & 127;
    W[idx] = f2bf(w2p[h * 128 + (k & 63) * 2 + (k >> 6)]);
  } else if (idx < 16384) {
    int i = idx - 8192; int h = i >> 7, k = i & 127;
    W[idx] = f2bf(t1p[(k & 63) * 128 + h * 2 + (k >> 6)]);
  } else if (idx < 24576) {
    int i = idx - 16384; int h = i >> 7, k = i & 127;
    W[idx] = f2bf(t2p[(k & 63) * 128 + h * 2 + (k >> 6)]);
  } else if (idx < 25088) {
    int i = idx - 24576;            // 0..511
    float* F = (float*)(W + 24576);
    int h = i & 63, sel = i >> 6;
    float val;
    if (sel == 0)      val = g1[h] * __builtin_amdgcn_rsqf(v1[h] + 1e-5f);
    else if (sel == 1) { float s = g1[h] * __builtin_amdgcn_rsqf(v1[h] + 1e-5f);
                         val = (b1[h] - m1[h]) * s + be1[h]; }
    else if (sel == 2) val = g2[h] * __builtin_amdgcn_rsqf(v2[h] + 1e-5f);
    else if (sel == 3) { float s = g2[h] * __builtin_amdgcn_rsqf(v2[h] + 1e-5f);
                         val = (b2[h] - m2[h]) * s + be2[h]; }
    else if (sel == 4) val = g3[h] * __builtin_amdgcn_rsqf(v3[h] + 1e-5f);
    else if (sel == 5) { float s = g3[h] * __builtin_amdgcn_rsqf(v3[h] + 1e-5f);
                         val = (tb1[h] - m3[h]) * s + be3[h]; }
    else if (sel == 6) val = 1.0f;
    else               val = tb2[h];
    F[i] = val;
  } else if (idx >= 25600 && idx < 27648) {
    // W1a[h][k=2c+d], k<12 real, else 0  (w1p layout [h][c][d] = h*12+k)
    int i = idx - 25600; int h = i >> 5, k = i & 31;
    W[idx] = (k < 12) ? f2bf(w1p[h * 12 + k]) : (uint16_t)0;
  }
}

// ============================ conv stack ===================================
#define YT   72
#define NROW 84
#define XST  40    // xsb row stride (uint16)

template<int PHASE>
__device__ __forceinline__ void mfma_phase(
    const uint16_t* yin, uint16_t* yout, uint16_t* Xg,
    const uint16_t* __restrict__ wAg,          // global A-layout [64][128]
    const float* __restrict__ p_sc, const float* __restrict__ p_tc,
    int lane, int wv, int l0)
{
  const int m0 = wv * 16;
  const int lm = lane & 15, lq = lane >> 4;
  bf16x8 af[4];
#pragma unroll
  for (int kc = 0; kc < 4; ++kc)
    af[kc] = *(const bf16x8*)&wAg[(m0 + lm) * 128 + kc * 32 + lq * 8];
  float scr[4], tcr[4];
#pragma unroll
  for (int r = 0; r < 4; ++r) {
    int hr = m0 + lq * 4 + r;
    scr[r] = p_sc[hr]; tcr[r] = p_tc[hr];
  }
  const f32x4 Z = {0.f, 0.f, 0.f, 0.f};
#pragma unroll
  for (int nt = 0; nt < 5; ++nt) {
    f32x4 acc = Z;
#pragma unroll
    for (int kc = 0; kc < 4; ++kc) {
      int half = kc >> 1;
      int rT = nt * 16 + lm + 1 + (PHASE == 2 ? half : -half);
      bf16x8 bf_ = *(const bf16x8*)&yin[rT * YT + (kc & 1) * 32 + lq * 8];
      acc = MFMA16(af[kc], bf_, acc);
    }
    int il = nt * 16 + lm;
    int gl = l0 - 2 + il;
    // packed epilogue: 4 outputs share il/gl (uniform mask), contiguous in h
    float v0 = fmaxf(acc[0] * scr[0] + tcr[0], 0.f);
    float v1 = fmaxf(acc[1] * scr[1] + tcr[1], 0.f);
    float v2 = fmaxf(acc[2] * scr[2] + tcr[2], 0.f);
    float v3 = fmaxf(acc[3] * scr[3] + tcr[3], 0.f);
    uint32_t p0 = cvtpk(v0, v1), p1 = cvtpk(v2, v3);
    if constexpr (PHASE == 2) {
      if (!(gl >= 0 && gl < 1022)) { p0 = 0; p1 = 0; }
      if (il < 66) {
        uint32_t* dst = (uint32_t*)&yout[(il + 1) * YT + m0 + lq * 4];
        dst[0] = p0; dst[1] = p1;
      }
    } else if constexpr (PHASE == 3) {
      if (!(gl >= 0 && gl < 1023)) { p0 = 0; p1 = 0; }
      if (il >= 1 && il < 66) {
        uint32_t* dst = (uint32_t*)&yout[(il + 1) * YT + m0 + lq * 4];
        dst[0] = p0; dst[1] = p1;
      }
    } else {
      if (il >= 2 && il < 66) {     // gl then always in [l0, l0+64)
        uint2 st; st.x = p0; st.y = p1;
        *(uint2*)&Xg[(size_t)gl * 64 + m0 + lq * 4] = st;
      }
    }
  }
}

__global__ __launch_bounds__(256, 6) void conv_stack_k(
    const float* __restrict__ inp,
    const float* __restrict__ F,
    const uint16_t* __restrict__ W1a, const uint16_t* __restrict__ W2a,
    const uint16_t* __restrict__ T1a, const uint16_t* __restrict__ T2a,
    uint16_t* __restrict__ X)
{
  __shared__ __align__(16) uint16_t yTA[NROW * YT];
  __shared__ __align__(16) uint16_t yTB[NROW * YT];
  __shared__ __align__(16) uint16_t xsb[80 * XST];  // phase-1 B tile [il][k]
  const int tid  = threadIdx.x;
  const int lane = tid & 63;
  const int wv   = tid >> 6;
  const int t    = blockIdx.y;
  const int l0   = blockIdx.x * 64;
  const int lm   = lane & 15, lq = lane >> 4;
  const f32x4 Z = {0.f, 0.f, 0.f, 0.f};

  // zero xsb rows 0..71 (valid-output region; rows 72..79 garbage-tolerated)
  for (int i = tid; i < 72 * XST / 8; i += 256)
    ((int4*)xsb)[i] = int4{0, 0, 0, 0};
  __syncthreads();

  // stage x -> xsb[il][2c+d] (bf16): element (c, il) feeds d=0 of row il and
  // d=1 of row il-1. gl outside [0,1024) stays zero. Coalesced global reads.
  for (int i = tid; i < 432; i += 256) {
    int c = i % 6, il = i / 6;
    int gl = l0 - 2 + il;
    if (gl >= 0 && gl < 1024) {
      uint16_t v = f2bf(inp[(size_t)t * 6144 + (size_t)gl * 6 + c]);
      xsb[il * XST + 2 * c] = v;
      if (il > 0) xsb[(il - 1) * XST + 2 * c + 1] = v;
    }
  }
  __syncthreads();

  // ---- phase 1 (MFMA): y1 = relu(bn1(conv1(x))), write yTA rows 1..67
  {
    const int m0 = wv * 16;
    bf16x8 af = *(const bf16x8*)&W1a[(m0 + lm) * 32 + lq * 8];
    float scr[4], tcr[4];
#pragma unroll
    for (int r = 0; r < 4; ++r) {
      int hr = m0 + lq * 4 + r;
      scr[r] = F[hr]; tcr[r] = F[64 + hr];
    }
#pragma unroll
    for (int nt = 0; nt < 5; ++nt) {
      bf16x8 bf_ = *(const bf16x8*)&xsb[(nt * 16 + lm) * XST + lq * 8];
      f32x4 acc = MFMA16(af, bf_, Z);
      int il = nt * 16 + lm;
      int gl = l0 - 2 + il;
      float v0 = fmaxf(acc[0] * scr[0] + tcr[0], 0.f);
      float v1 = fmaxf(acc[1] * scr[1] + tcr[1], 0.f);
      float v2 = fmaxf(acc[2] * scr[2] + tcr[2], 0.f);
      float v3 = fmaxf(acc[3] * scr[3] + tcr[3], 0.f);
      uint32_t p0 = cvtpk(v0, v1), p1 = cvtpk(v2, v3);
      if (!(gl >= 0 && gl < 1023)) { p0 = 0; p1 = 0; }
      if (il < 67) {
        uint32_t* dst = (uint32_t*)&yTA[(il + 1) * YT + m0 + lq * 4];
        dst[0] = p0; dst[1] = p1;
      }
    }
  }
  __syncthreads();

  mfma_phase<2>(yTA, yTB, nullptr, W2a, F + 128, F + 192, lane, wv, l0);
  __syncthreads();
  mfma_phase<3>(yTB, yTA, nullptr, T1a, F + 256, F + 320, lane, wv, l0);
  __syncthreads();
  mfma_phase<4>(yTA, nullptr, X + (size_t)(t + 1) * 65536, T2a,
                F + 384, F + 448, lane, wv, l0);
}

// ============================== LSTM v15 (unchanged) ========================
// 256 blocks x 320 threads: waves 0-3 compute (4 rows, 1 cell/lane), wave 4
// projection. 8 barriers per 8-step batch in BOTH paths.
#define HSTR 72

#define BARRIER() do {                                                         \
    asm volatile("s_waitcnt lgkmcnt(0)" ::: "memory");                         \
    __builtin_amdgcn_s_barrier();                                              \
    asm volatile("" ::: "memory");                                             \
  } while (0)

// compute step; K_ literal 0..7 (hh slot), DG literal dribble gate
#define LSTM_STEP(T_, K_, AXC, DG, XD, AXN) do {                               \
    bf16x8 hf0_ = *(const bf16x8*)&hh[((K_) + 7) & 7][(lm >> 2) * HSTR + lq * 8];      \
    bf16x8 hf1_ = *(const bf16x8*)&hh[((K_) + 7) & 7][(lm >> 2) * HSTR + 32 + lq * 8]; \
    f32x4 z0_ = MFMA16(hf1_, bfr[0][3], MFMA16(hf0_, bfr[0][2], AXC[0]));      \
    f32x4 z1_ = MFMA16(hf1_, bfr[1][3], MFMA16(hf0_, bfr[1][2], AXC[1]));      \
    f32x4 z2_ = MFMA16(hf1_, bfr[2][3], MFMA16(hf0_, bfr[2][2], AXC[2]));      \
    f32x4 z3_ = MFMA16(hf1_, bfr[3][3], MFMA16(hf0_, bfr[3][2], AXC[3]));      \
    float ii_ = fsig2(z0_[(K_) & 3]);                                          \
    float ff_ = fsig2(z1_[(K_) & 3]);                                          \
    float gg_ = ftanh2(z2_[(K_) & 3]);                                         \
    float oo_ = fsig2(z3_[(K_) & 3]);                                          \
    creg  = ff_ * creg + ii_ * gg_;                                            \
    float th_ = 1.f - 2.f * frcp(1.f + __builtin_amdgcn_exp2f(creg * 2.88539008177793f)); \
    hprev = oo_ * th_;                                                         \
    uint32_t hw_;                                                              \
    asm("v_cvt_pk_bf16_f32 %0, %1, %2" : "=v"(hw_) : "v"(hprev), "v"(0.f));    \
    hh[(K_)][lq * HSTR + hcol] = (uint16_t)hw_;                                \
    AXN[DG] = MFMA16(XD[1], bfr[DG][1], MFMA16(XD[0], bfr[DG][0], seeds[DG])); \
    BARRIER();                                                                 \
  } while (0)

__global__ __launch_bounds__(320) void lstm_k(
    const float* __restrict__ h0p, const float* __restrict__ c0p,
    const float* __restrict__ wihp, const float* __restrict__ whhp,
    const float* __restrict__ bihp, const float* __restrict__ bhhp,
    const float* __restrict__ owp, const float* __restrict__ obp,
    uint16_t* __restrict__ Xb, float* __restrict__ outp)
{
  __shared__ __align__(16) uint16_t hh[8][4 * HSTR];   // 8-deep h history
  const int tid  = threadIdx.x;
  const int lane = tid & 63;
  const int wv   = tid >> 6;                // 0..4
  const int lm   = lane & 15;
  const int lq   = lane >> 4;
  const int l0   = blockIdx.x << 2;         // 4 batch rows per block
  const f32x4 Z4 = {0.f, 0.f, 0.f, 0.f};

  // stage h0 -> hh[7] ("step -1")
  if (tid < 256) {
    int row = tid >> 6, col = tid & 63;
    hh[7][row * HSTR + col] = f2bf(h0p[(size_t)(l0 + row) * 64 + col]);
  }
  __syncthreads();

  if (wv == 4) {
    // ---------------- projection wave ----------------
    bf16x8 owf0 = {0, 0, 0, 0, 0, 0, 0, 0}, owf1 = {0, 0, 0, 0, 0, 0, 0, 0};
    if (lm == 0) {
#pragma unroll
      for (int j = 0; j < 8; ++j) {
        owf0[j] = (short)f2bf(owp[lq * 8 + j]);
        owf1[j] = (short)f2bf(owp[32 + lq * 8 + j]);
      }
    }
    float obv = obp[0];
#pragma unroll 1
    for (int t0 = 0; t0 < 512; t0 += 8) {
      if (t0 > 0) {   // steps t0-4..t0-1 live in slots 4..7
        bf16x8 pa0 = *(const bf16x8*)&hh[4 + (lm & 3)][(lm >> 2) * HSTR + lq * 8];
        bf16x8 pa1 = *(const bf16x8*)&hh[4 + (lm & 3)][(lm >> 2) * HSTR + 32 + lq * 8];
        f32x4 pr = MFMA16(pa1, owf1, MFMA16(pa0, owf0, Z4));
        if (lm == 0) {
          outp[(size_t)(t0 - 4) * 1024 + l0 + lq] = pr[0] + obv;
          outp[(size_t)(t0 - 3) * 1024 + l0 + lq] = pr[1] + obv;
          outp[(size_t)(t0 - 2) * 1024 + l0 + lq] = pr[2] + obv;
          outp[(size_t)(t0 - 1) * 1024 + l0 + lq] = pr[3] + obv;
        }
      }
      BARRIER(); BARRIER(); BARRIER(); BARRIER();   // steps t0+0..t0+3
      {             // steps t0+0..t0+3 now live in slots 0..3
        bf16x8 pa0 = *(const bf16x8*)&hh[(lm & 3)][(lm >> 2) * HSTR + lq * 8];
        bf16x8 pa1 = *(const bf16x8*)&hh[(lm & 3)][(lm >> 2) * HSTR + 32 + lq * 8];
        f32x4 pr = MFMA16(pa1, owf1, MFMA16(pa0, owf0, Z4));
        if (lm == 0) {
          outp[(size_t)(t0 + 0) * 1024 + l0 + lq] = pr[0] + obv;
          outp[(size_t)(t0 + 1) * 1024 + l0 + lq] = pr[1] + obv;
          outp[(size_t)(t0 + 2) * 1024 + l0 + lq] = pr[2] + obv;
          outp[(size_t)(t0 + 3) * 1024 + l0 + lq] = pr[3] + obv;
        }
      }
      BARRIER(); BARRIER(); BARRIER(); BARRIER();   // steps t0+4..t0+7
    }
    // post-loop: steps 508-511 from slots 4-7
    {
      bf16x8 pa0 = *(const bf16x8*)&hh[4 + (lm & 3)][(lm >> 2) * HSTR + lq * 8];
      bf16x8 pa1 = *(const bf16x8*)&hh[4 + (lm & 3)][(lm >> 2) * HSTR + 32 + lq * 8];
      f32x4 pr = MFMA16(pa1, owf1, MFMA16(pa0, owf0, Z4));
      if (lm == 0) {
        outp[(size_t)508 * 1024 + l0 + lq] = pr[0] + obv;
        outp[(size_t)509 * 1024 + l0 + lq] = pr[1] + obv;
        outp[(size_t)510 * 1024 + l0 + lq] = pr[2] + obv;
        outp[(size_t)511 * 1024 + l0 + lq] = pr[3] + obv;
      }
    }
    return;
  }

  // ---------------- compute waves (0-3) ----------------
  const int hcol = (wv << 4) | lm;
  const float L2E = 1.44269504088896340736f;

  // B weights, pre-scaled: i,f,o x log2e ; g x 2*log2e
  bf16x8 bfr[4][4];
#pragma unroll
  for (int nt = 0; nt < 4; ++nt) {
    float sg = (nt == 2) ? 2.f * L2E : L2E;
    int n = nt * 64 + hcol;
#pragma unroll
    for (int kc = 0; kc < 4; ++kc) {
      int k0 = kc * 32 + lq * 8;
      const float* src = (k0 < 64) ? (wihp + (size_t)n * 64 + k0)
                                   : (whhp + (size_t)n * 64 + (k0 - 64));
      bf16x8 f;
#pragma unroll
      for (int j = 0; j < 8; ++j) f[j] = (short)f2bf(src[j] * sg);
      bfr[nt][kc] = f;
    }
  }
  float bi0 = (bihp[hcol]       + bhhp[hcol])       * L2E;
  float bi1 = (bihp[64 + hcol]  + bhhp[64 + hcol])  * L2E;
  float bi2 = (bihp[128 + hcol] + bhhp[128 + hcol]) * 2.f * L2E;
  float bi3 = (bihp[192 + hcol] + bhhp[192 + hcol]) * L2E;
  f32x4 seeds[4];
  seeds[0] = f32x4{bi0, bi0, bi0, bi0};
  seeds[1] = f32x4{bi1, bi1, bi1, bi1};
  seeds[2] = f32x4{bi2, bi2, bi2, bi2};
  seeds[3] = f32x4{bi3, bi3, bi3, bi3};

  // one cell per lane: (batch row lq, h-col hcol)
  float creg  = c0p[(size_t)(l0 + lq) * 64 + hcol];
  float hprev = 0.f;

  // running x pointers: batch t0 reads slots t0+1..t0+4
  const uint16_t* pA = Xb + (size_t)(1 + (lm & 3)) * 65536
                     + (size_t)(l0 + (lm >> 2)) * 64 + lq * 8;
  const uint16_t* pB = pA + (size_t)4 * 65536;
  bf16x8 xA[2], xB[2];
  xA[0] = *(const bf16x8*)pA; xA[1] = *(const bf16x8*)(pA + 32);
  pA += (size_t)8 * 65536;
  xB[0] = *(const bf16x8*)pB; xB[1] = *(const bf16x8*)(pB + 32);
  pB += (size_t)8 * 65536;

  f32x4 axA[4], axB[4];
#pragma unroll
  for (int g = 0; g < 4; ++g)
    axA[g] = MFMA16(xA[1], bfr[g][1], MFMA16(xA[0], bfr[g][0], seeds[g]));

#pragma unroll 1
  for (int t0 = 0; t0 < 512; t0 += 8) {
    if (t0 + 8 < 512) {          // xA <- batch t0+8 (dribbled at steps 4-7)
      xA[0] = *(const bf16x8*)pA; xA[1] = *(const bf16x8*)(pA + 32);
      pA += (size_t)8 * 65536;
    }
    LSTM_STEP(t0 + 0, 0, axA, 0, xB, axB);
    LSTM_STEP(t0 + 1, 1, axA, 1, xB, axB);
    LSTM_STEP(t0 + 2, 2, axA, 2, xB, axB);
    LSTM_STEP(t0 + 3, 3, axA, 3, xB, axB);
    if (t0 + 12 < 512) {         // xB <- batch t0+12 (dribbled next iter 0-3)
      xB[0] = *(const bf16x8*)pB; xB[1] = *(const bf16x8*)(pB + 32);
      pB += (size_t)8 * 65536;
    }
    LSTM_STEP(t0 + 4, 4, axB, 0, xA, axA);
    LSTM_STEP(t0 + 5, 5, axB, 1, xA, axA);
    LSTM_STEP(t0 + 6, 6, axB, 2, xA, axA);
    LSTM_STEP(t0 + 7, 7, axB, 3, xA, axA);
  }

  // hT at out+524288, cT at out+589824 (fp32)
  outp[524288 + (size_t)(l0 + lq) * 64 + hcol] = hprev;
  outp[589824 + (size_t)(l0 + lq) * 64 + hcol] = creg;
}

// ============================== launch =====================================
extern "C" void kernel_launch(void* const* d_in, const int* in_sizes, int n_in,
                              void* d_out, int out_size, void* d_ws, size_t ws_size,
                              hipStream_t stream)
{
  (void)in_sizes; (void)n_in; (void)out_size;
  if (ws_size < (size_t)513 * 65536 * 2) return;   // ws guard

  const float* inp = (const float*)d_in[0];
  const float* h0p = (const float*)d_in[1];
  const float* c0p = (const float*)d_in[2];
  const float* w1  = (const float*)d_in[3];
  const float* b1  = (const float*)d_in[4];
  const float* g1  = (const float*)d_in[5];
  const float* be1 = (const float*)d_in[6];
  const float* m1  = (const float*)d_in[7];
  const float* v1  = (const float*)d_in[8];
  const float* w2  = (const float*)d_in[9];
  const float* b2  = (const float*)d_in[10];
  const float* g2  = (const float*)d_in[11];
  const float* be2 = (const float*)d_in[12];
  const float* m2  = (const float*)d_in[13];
  const float* v2  = (const float*)d_in[14];
  const float* tw1 = (const float*)d_in[15];
  const float* tb1 = (const float*)d_in[16];
  const float* g3  = (const float*)d_in[17];
  const float* be3 = (const float*)d_in[18];
  const float* m3  = (const float*)d_in[19];
  const float* v3  = (const float*)d_in[20];
  const float* tw2 = (const float*)d_in[21];
  const float* tb2 = (const float*)d_in[22];
  const float* wih = (const float*)d_in[23];
  const float* whh = (const float*)d_in[24];
  const float* bih = (const float*)d_in[25];
  const float* bhh = (const float*)d_in[26];
  const float* ow  = (const float*)d_in[27];
  const float* ob  = (const float*)d_in[28];

  uint16_t* Xb   = (uint16_t*)d_ws;
  float*    outp = (float*)d_out;

  // slot 0: W2a[0,8192) T1a[8192,16384) T2a[16384,24576) F[24576,25600) W1a[25600,27648)
  const uint16_t* W2a = Xb;
  const uint16_t* T1a = Xb + 8192;
  const uint16_t* T2a = Xb + 16384;
  const float*    F   = (const float*)(Xb + 24576);
  const uint16_t* W1a = Xb + 25600;

  prep_k<<<108, 256, 0, stream>>>(w1, w2, tw1, tw2,
                                  g1, be1, m1, v1, b1,
                                  g2, be2, m2, v2, b2,
                                  g3, be3, m3, v3, tb1, tb2, Xb);
  conv_stack_k<<<dim3(16, 512), 256, 0, stream>>>(inp, F, W1a, W2a, T1a, T2a, Xb);
  lstm_k<<<256, 320, 0, stream>>>(h0p, c0p, wih, whh, bih, bhh, ow, ob, Xb, outp);
}